// Round 6
// baseline (728.632 us; speedup 1.0000x reference)
//
#include <hip/hip_runtime.h>
#include <cstddef>
#include <cstdint>

// ---------------- problem constants ----------------
// b=2, s=256, WIDTH=64, RANK=4, CLEVEL=1 (c=2), MLEVEL=2 (L=3), NB=4
// HID1=64, HID2=128

// ---------------- workspace layout (float offsets) ----------------
static constexpr size_t OFF_X1     = 0;          // 8388608
static constexpr size_t OFF_YL1    = 8388608;    // 2097152
static constexpr size_t OFF_YL2    = 10485760;   // 524288
static constexpr size_t OFF_HBF    = 11010048;   // bf16 h: 8388608 bf16 = 4194304 slots
static constexpr size_t OFF_H2PHI  = 15204352;   // 4194304
static constexpr size_t OFF_X2C    = 19398656;   // 2097152
static constexpr size_t OFF_CWTBF  = 21495808;   // 221184
static constexpr size_t OFF_Q1BF   = 21716992;   // 4096
static constexpr size_t OFF_GPART  = 21721088;   // 512*8192 = 4194304
static constexpr size_t OFF_SVP    = 25915392;   // 512*64 = 32768
static constexpr size_t OFF_G      = 25948160;   // 16384
static constexpr size_t OFF_SV     = 25964544;   // 128
// end = 25964672 floats (~104 MB) <= proven-available 134.3 MB

typedef __attribute__((ext_vector_type(8)))  short bf16x8_t;   // 8 bf16 in 4 VGPRs
typedef __attribute__((ext_vector_type(16))) float f32x16_t;   // 32x32 MFMA acc

// ---------------- helpers ----------------
__device__ inline float wave_sum64(float v) {
    v += __shfl_xor(v, 1);
    v += __shfl_xor(v, 2);
    v += __shfl_xor(v, 4);
    v += __shfl_xor(v, 8);
    v += __shfl_xor(v, 16);
    v += __shfl_xor(v, 32);
    return v;
}

__device__ inline unsigned short f2bf(float f) {   // round-to-nearest-even
    uint32_t u = __float_as_uint(f);
    uint32_t r = u + 0x7FFFu + ((u >> 16) & 1u);
    return (unsigned short)(r >> 16);
}

// full-res flat pixel index of coarse pixel (b, n): n in [0,16384)
__device__ inline size_t fullpix(int b, int n) {
    return (size_t)(b * 65536 + (n >> 7) * 512 + ((n & 127) << 1));
}

struct Lerp { int i0, i1; float f; };
__device__ inline Lerp lcoord(int o, float r, float off, int Sin) {
    float s = fmaxf(fmaf((float)o, r, off), 0.f);
    Lerp L;
    L.i0 = (int)s;
    L.f  = s - (float)L.i0;
    L.i1 = min(L.i0 + 1, Sin - 1);
    return L;
}
__device__ inline float bilerp64(const float* __restrict__ base, int Sin,
                                 const Lerp& ly, const Lerp& lx, int lane) {
    float v00 = base[((size_t)(ly.i0 * Sin + lx.i0)) * 64 + lane];
    float v01 = base[((size_t)(ly.i0 * Sin + lx.i1)) * 64 + lane];
    float v10 = base[((size_t)(ly.i1 * Sin + lx.i0)) * 64 + lane];
    float v11 = base[((size_t)(ly.i1 * Sin + lx.i1)) * 64 + lane];
    float a = v00 + lx.f * (v01 - v00);
    float b = v10 + lx.f * (v11 - v10);
    return a + ly.f * (b - a);
}

// ---------------- weight transforms ----------------
// convW[i][l][oc][ic][3][3] f32 -> cwtbf[i*3+l][oc][tap*64+ic] bf16
__global__ __launch_bounds__(256) void k_transpose_convw_bf(const float* __restrict__ w,
                                                            unsigned short* __restrict__ wt) {
    int idx = blockIdx.x * 256 + threadIdx.x;     // 12*64*576 = 442368
    if (idx >= 442368) return;
    int k    = idx % 576;
    int rest = idx / 576;
    int oc   = rest & 63;
    int il   = rest >> 6;
    int tap  = k >> 6;
    int ic   = k & 63;
    wt[idx] = f2bf(w[((size_t)(il * 64 + oc) * 64 + ic) * 9 + tap]);
}
// q1W[64][128] f32 -> q1bf[j][k] bf16 (transposed)
__global__ __launch_bounds__(256) void k_transpose_q1bf(const float* __restrict__ w,
                                                        unsigned short* __restrict__ wt) {
    int idx = blockIdx.x * 256 + threadIdx.x;     // 8192
    if (idx >= 8192) return;
    int k = idx & 63;
    int j = idx >> 6;
    wt[j * 64 + k] = f2bf(w[k * 128 + j]);
}

// ---------------- lift: h = [a0,a1,x] @ pW + pb (writes bf16 NHWC) ----------------
__global__ __launch_bounds__(256) void k_lift(const float* __restrict__ x,
                                              const float* __restrict__ a,
                                              const float* __restrict__ pW,
                                              const float* __restrict__ pb,
                                              unsigned short* __restrict__ hbf) {
    int p = blockIdx.x * 256 + threadIdx.x;       // 131072
    float a0 = a[(size_t)p * 2 + 0];
    float a1 = a[(size_t)p * 2 + 1];
    float xv = x[p];
    float vals[64];
#pragma unroll
    for (int c = 0; c < 64; ++c)
        vals[c] = fmaf(a0, pW[c], fmaf(a1, pW[64 + c], fmaf(xv, pW[128 + c], pb[c])));
    unsigned short us[64];
#pragma unroll
    for (int c = 0; c < 64; ++c) us[c] = f2bf(vals[c]);
    unsigned short* bp = hbf + (size_t)p * 64;
#pragma unroll
    for (int c = 0; c < 64; c += 8)
        *(uint4*)(bp + c) = *(uint4*)(us + c);
}

// ---------------- MFMA conv 3x3 SAME (64->64), oc-split for 2 blocks/CU ----------------
// Each block: 16x16 px tile x 32 output channels. Grid 1344.
__global__ __launch_bounds__(256) void k_conv_mfma(
    const unsigned short* __restrict__ hbf,   // [2][256][256][64] bf16
    const unsigned short* __restrict__ wbf,   // [12][64][576] bf16
    const float* __restrict__ convb,          // [12][64]
    float* __restrict__ x1, float* __restrict__ yl1, float* __restrict__ yl2,
    int iter) {
    __shared__ unsigned short Ald[20736];     // 324 px * 64 ic  (41472 B)
    __shared__ unsigned short Bld[18432];     // 32 oc * 576 k   (36864 B)

    int bid = blockIdx.x;
    int lvl, q2_, Sl, st, tpr;
    if (bid < 1024)      { lvl = 0; q2_ = bid;        Sl = 256; st = 1; tpr = 16; }
    else if (bid < 1280) { lvl = 1; q2_ = bid - 1024; Sl = 128; st = 2; tpr = 8;  }
    else                 { lvl = 2; q2_ = bid - 1280; Sl = 64;  st = 4; tpr = 4;  }
    int tix = q2_ >> 1;
    int oc0 = (q2_ & 1) << 5;
    int tpb = tpr * tpr;
    int b = tix / tpb;
    int r = tix - b * tpb;
    int y0 = (r / tpr) * 16, x0 = (r % tpr) * 16;
    int t = threadIdx.x;

    // ---- stage A: 18x18 halo x 64 ic, zero-padded at image edges ----
    for (int c = t; c < 2592; c += 256) {       // 324 rows * 8 slots(16B)
        int lin = c >> 3, slot = c & 7;
        int ty = lin / 18, tx = lin - ty * 18;
        int oy = y0 + ty - 1, ox = x0 + tx - 1;
        uint4 val = make_uint4(0u, 0u, 0u, 0u);
        if ((unsigned)oy < (unsigned)Sl && (unsigned)ox < (unsigned)Sl) {
            const unsigned short* src =
                hbf + (((size_t)(b * 256 + oy * st) * 256 + ox * st) << 6) + (slot << 3);
            val = *(const uint4*)src;
        }
        int byte = (lin << 7) + (((slot ^ (lin & 7))) << 4);
        *(uint4*)((char*)Ald + byte) = val;
    }
    // ---- stage B: 32 oc rows of weights for this (iter,lvl,oc0) ----
    {
        const unsigned short* wsrc = wbf + (size_t)(iter * 3 + lvl) * 36864 + (size_t)oc0 * 576;
        int ocl = t >> 3, q = t & 7;
#pragma unroll
        for (int j = 0; j < 18; ++j) {
            int ke = q * 72 + j * 4;                    // bf16 elems
            uint2 v = *(const uint2*)(wsrc + ocl * 576 + ke);
            int byte = (ocl * 1152 + (ke << 1)) ^ ((ocl & 7) << 4);
            *(uint2*)((char*)Bld + byte) = v;
        }
    }
    __syncthreads();

    // ---- compute ----
    int w    = t >> 6;
    int lane = t & 63;
    int lo   = lane & 31;
    int hi   = lane >> 5;
    f32x16_t acc00 = {}, acc10 = {};

    int yA0 = 4 * w + (lo >> 4);
    int xA  = lo & 15;
#pragma unroll 3
    for (int tap = 0; tap < 9; ++tap) {
        int dy = tap / 3, dx = tap - dy * 3;
        int lin0 = (yA0 + dy) * 18 + (xA + dx);
        int lin1 = lin0 + 36;
#pragma unroll
        for (int kq = 0; kq < 4; ++kq) {
            int icb = (kq << 5) + (hi << 4);
            int a0b = ((lin0 << 7) + icb) ^ ((lin0 & 7) << 4);
            int a1b = ((lin1 << 7) + icb) ^ ((lin1 & 7) << 4);
            bf16x8_t va0 = *(bf16x8_t*)((char*)Ald + a0b);
            bf16x8_t va1 = *(bf16x8_t*)((char*)Ald + a1b);
            int kk  = tap * 128 + icb;
            int b0b = (lo * 1152 + kk) ^ ((lo & 7) << 4);
            bf16x8_t vb0 = *(bf16x8_t*)((char*)Bld + b0b);
            acc00 = __builtin_amdgcn_mfma_f32_32x32x16_bf16(va0, vb0, acc00, 0, 0, 0);
            acc10 = __builtin_amdgcn_mfma_f32_32x32x16_bf16(va1, vb0, acc10, 0, 0, 0);
        }
    }

    // ---- store ----
    float* out = (lvl == 0) ? x1 : (lvl == 1 ? yl1 : yl2);
    float bias0 = convb[(iter * 3 + lvl) * 64 + oc0 + lo];
#pragma unroll
    for (int reg = 0; reg < 16; ++reg) {
        int row = (reg & 3) + 8 * (reg >> 2) + 4 * hi;
        int yt  = 4 * w + (row >> 4);
        int xt  = row & 15;
        size_t pix0 = ((size_t)(b * Sl + y0 + yt) * Sl + (x0 + xt)) << 6;
        out[pix0 + oc0 + lo] = acc00[reg] + bias0;
        size_t pix1 = ((size_t)(b * Sl + y0 + yt + 2) * Sl + (x0 + xt)) << 6;
        out[pix1 + oc0 + lo] = acc10[reg] + bias0;
    }
}

// ---------------- fused mlp12 + gpart: H2psi in LDS only; H2phi to global ----------------
// grid 512: block = 64 coarse px. Gpart[blk] + svpart[blk] non-atomic.
__global__ __launch_bounds__(256) void k_mlpg(
    const float* __restrict__ a, const float* __restrict__ x,
    const float* __restrict__ psiW1, const float* __restrict__ psib1,
    const float* __restrict__ psiW2, const float* __restrict__ psib2,
    const float* __restrict__ phiW1, const float* __restrict__ phib1,
    const float* __restrict__ phiW2, const float* __restrict__ phib2,
    const unsigned short* __restrict__ hbf,
    float* __restrict__ H2phi,
    float* __restrict__ Gpart, float* __restrict__ svpart) {
    __shared__ float vt[64][64];
    __shared__ float h2t[8192];      // [64 px][128 j] f32, 16B-granule XOR swizzle
    int blk = blockIdx.x;            // 512
    int b = blk >> 8;
    int n0 = (blk & 255) << 6;
    int t = threadIdx.x;

    // ---- stage v (bf16 -> f32), 4 threads per px ----
    {
        int pxq = t >> 2, qq = t & 3;
        const unsigned short* src = hbf + fullpix(b, n0 + pxq) * 64 + qq * 16;
        uint4 u0 = *(const uint4*)src;
        uint4 u1 = *(const uint4*)(src + 8);
        unsigned uv[8] = {u0.x, u0.y, u0.z, u0.w, u1.x, u1.y, u1.z, u1.w};
        float* dst = &vt[pxq][qq * 16];
#pragma unroll
        for (int i = 0; i < 8; ++i) {
            dst[2 * i]     = __uint_as_float((uv[i] & 0xFFFFu) << 16);
            dst[2 * i + 1] = __uint_as_float(uv[i] & 0xFFFF0000u);
        }
    }

    // ---- MLPs: lane = px, wave = j-quadrant ----
    int px = t & 63;
    int j0 = (t >> 6) << 5;          // 0/32/64/96 (wave-uniform)
    int n = n0 + px;
    size_t apix = fullpix(b, n);
    float a0 = a[apix * 2], a1 = a[apix * 2 + 1], xv = x[apix];

    {   // psi -> h2t (LDS, swizzled)
        float acc[32];
#pragma unroll
        for (int j = 0; j < 32; ++j) acc[j] = psib2[j0 + j];
#pragma unroll 1
        for (int k = 0; k < 64; ++k) {
            float h1 = fmaxf(fmaf(a0, psiW1[k], fmaf(a1, psiW1[64 + k],
                             fmaf(xv, psiW1[128 + k], psib1[k]))), 0.f);
            const float* wr = psiW2 + k * 128 + j0;
#pragma unroll
            for (int j = 0; j < 32; ++j) acc[j] = fmaf(h1, wr[j], acc[j]);
        }
#pragma unroll
        for (int j4 = 0; j4 < 8; ++j4) {
            int byte = (px * 512 + (j0 + j4 * 4) * 4) ^ ((px & 7) << 4);
            *(float4*)((char*)h2t + byte) =
                make_float4(fmaxf(acc[j4 * 4], 0.f),     fmaxf(acc[j4 * 4 + 1], 0.f),
                            fmaxf(acc[j4 * 4 + 2], 0.f), fmaxf(acc[j4 * 4 + 3], 0.f));
        }
    }
    {   // phi -> global
        float acc[32];
#pragma unroll
        for (int j = 0; j < 32; ++j) acc[j] = phib2[j0 + j];
#pragma unroll 1
        for (int k = 0; k < 64; ++k) {
            float h1 = fmaxf(fmaf(a0, phiW1[k], fmaf(a1, phiW1[64 + k],
                             fmaf(xv, phiW1[128 + k], phib1[k]))), 0.f);
            const float* wr = phiW2 + k * 128 + j0;
#pragma unroll
            for (int j = 0; j < 32; ++j) acc[j] = fmaf(h1, wr[j], acc[j]);
        }
        float* op = H2phi + ((size_t)(b * 16384 + n)) * 128 + j0;
#pragma unroll
        for (int j4 = 0; j4 < 8; ++j4)
            *(float4*)(op + j4 * 4) =
                make_float4(fmaxf(acc[j4 * 4], 0.f),     fmaxf(acc[j4 * 4 + 1], 0.f),
                            fmaxf(acc[j4 * 4 + 2], 0.f), fmaxf(acc[j4 * 4 + 3], 0.f));
    }
    __syncthreads();

    // ---- outer product: Gpart[blk][w][k] += v[n][w] * h2psi[n][k] ----
    int wt_ = (t >> 5) << 3;         // 0..56
    int kt  = (t & 31) << 2;         // 0..124
    float acc[8][4];
#pragma unroll
    for (int i = 0; i < 8; ++i)
#pragma unroll
        for (int j = 0; j < 4; ++j) acc[i][j] = 0.f;

#pragma unroll 4
    for (int nn = 0; nn < 64; ++nn) {
        int hb = (nn * 512 + kt * 4) ^ ((nn & 7) << 4);
        float4 hv = *(float4*)((char*)h2t + hb);
        float4 v0 = *(float4*)&vt[nn][wt_];
        float4 v1 = *(float4*)&vt[nn][wt_ + 4];
        float vv[8] = {v0.x, v0.y, v0.z, v0.w, v1.x, v1.y, v1.z, v1.w};
        float hh[4] = {hv.x, hv.y, hv.z, hv.w};
#pragma unroll
        for (int i = 0; i < 8; ++i)
#pragma unroll
            for (int j = 0; j < 4; ++j) acc[i][j] = fmaf(vv[i], hh[j], acc[i][j]);
    }

    float* gp = Gpart + (size_t)blk * 8192;
#pragma unroll
    for (int i = 0; i < 8; ++i)
        *(float4*)&gp[(wt_ + i) * 128 + kt] =
            make_float4(acc[i][0], acc[i][1], acc[i][2], acc[i][3]);

    if (t < 64) {
        float s = 0.f;
#pragma unroll 8
        for (int p = 0; p < 64; ++p) s += vt[p][t];
        svpart[blk * 64 + t] = s;
    }
}

// ---------------- reduce: G = sum Gpart; sv = sum svpart (grid 258) ----------------
__global__ __launch_bounds__(256) void k_gred(const float* __restrict__ Gpart,
                                              const float* __restrict__ svpart,
                                              float* __restrict__ G,
                                              float* __restrict__ sv) {
    __shared__ float red[4][64];
    int blk = blockIdx.x;
    int t = threadIdx.x;
    if (blk < 256) {
        int b  = blk >> 7;
        int es = (blk & 127) << 6;
        int e  = es + (t & 63);
        int cg = t >> 6;
        float s = 0.f;
        const float* gp = Gpart + ((size_t)(b * 256 + cg * 64)) * 8192 + e;
#pragma unroll 8
        for (int c = 0; c < 64; ++c) s += gp[(size_t)c * 8192];
        red[cg][t & 63] = s;
        __syncthreads();
        if (t < 64)
            G[b * 8192 + es + t] = red[0][t] + red[1][t] + red[2][t] + red[3][t];
    } else {
        int b = blk - 256;
        int w = t & 63, cg = t >> 6;
        float s = 0.f;
        const float* sp = svpart + ((size_t)(b * 256 + cg * 64)) * 64 + w;
#pragma unroll 8
        for (int c = 0; c < 64; ++c) s += sp[c * 64];
        red[cg][w] = s;
        __syncthreads();
        if (t < 64) sv[b * 64 + t] = red[0][t] + red[1][t] + red[2][t] + red[3][t];
    }
}

// ---------------- fused yc + x2c: ybar,C,D in LDS, then x2c GEMM ----------------
__global__ __launch_bounds__(256) void k_x2cyc(const float* __restrict__ G,
                                               const float* __restrict__ sv,
                                               const float* __restrict__ W3psi,
                                               const float* __restrict__ b3psi,
                                               const float* __restrict__ W3phi,
                                               const float* __restrict__ b3phi,
                                               const float* __restrict__ H2phi,
                                               float* __restrict__ x2c) {
    __shared__ float ybar[256];
    __shared__ float cl[8192];
    __shared__ float Dl[64];
    int blk = blockIdx.x;            // 128
    int b = blk >> 6;
    int px0 = blk << 8;
    int t = threadIdx.x;

    {   // ybar (redundant per block; 32K FMA)
        int o = t, w = o >> 2;
        float s = b3psi[o] * sv[b * 64 + w];
        const float* gp = &G[(size_t)(b * 64 + w) * 128];
#pragma unroll 4
        for (int k = 0; k < 128; ++k) s = fmaf(W3psi[k * 256 + o], gp[k], s);
        ybar[o] = s * (1.f / 16384.f);
    }
    __syncthreads();
#pragma unroll
    for (int rep = 0; rep < 32; ++rep) {
        int e = rep * 256 + t;       // C: 8192 elems
        int w = e >> 7, k = e & 127;
        const float* wp = &W3phi[k * 256 + w * 4];
        cl[e] = fmaf(wp[0], ybar[w * 4],
                fmaf(wp[1], ybar[w * 4 + 1],
                fmaf(wp[2], ybar[w * 4 + 2], wp[3] * ybar[w * 4 + 3])));
    }
    if (t < 64) {
        Dl[t] = b3phi[t * 4] * ybar[t * 4] + b3phi[t * 4 + 1] * ybar[t * 4 + 1]
              + b3phi[t * 4 + 2] * ybar[t * 4 + 2] + b3phi[t * 4 + 3] * ybar[t * 4 + 3];
    }
    __syncthreads();

    int w0 = __builtin_amdgcn_readfirstlane((t >> 6) << 4);
    int px = px0 + ((t & 63) << 2);
    float acc[4][16];
#pragma unroll
    for (int i = 0; i < 4; ++i)
#pragma unroll
        for (int j = 0; j < 16; ++j) acc[i][j] = 0.f;

    const float* hbase = H2phi + (size_t)px * 128;
#pragma unroll 2
    for (int kq = 0; kq < 32; ++kq) {
        float4 h2q[4];
#pragma unroll
        for (int i = 0; i < 4; ++i) h2q[i] = *(const float4*)&hbase[i * 128 + kq * 4];
#pragma unroll
        for (int j = 0; j < 16; ++j) {
            float4 cq = *(float4*)&cl[(w0 + j) * 128 + kq * 4];
#pragma unroll
            for (int i = 0; i < 4; ++i) {
                acc[i][j] = fmaf(h2q[i].x, cq.x, acc[i][j]);
                acc[i][j] = fmaf(h2q[i].y, cq.y, acc[i][j]);
                acc[i][j] = fmaf(h2q[i].z, cq.z, acc[i][j]);
                acc[i][j] = fmaf(h2q[i].w, cq.w, acc[i][j]);
            }
        }
    }
#pragma unroll
    for (int i = 0; i < 4; ++i) {
        float* op = &x2c[(size_t)(px + i) * 64 + w0];
#pragma unroll
        for (int j = 0; j < 16; j += 4) {
            float4 o4 = make_float4(acc[i][j]     + Dl[w0 + j],
                                    acc[i][j + 1] + Dl[w0 + j + 1],
                                    acc[i][j + 2] + Dl[w0 + j + 2],
                                    acc[i][j + 3] + Dl[w0 + j + 3]);
            *(float4*)(op + j) = o4;
        }
    }
}

// ---------------- epilogue: h = LN(x1 + up(yl1) + up(yl2) + up(x2c)); writes bf16 ----------------
__global__ __launch_bounds__(256) void k_epilogue(const float* __restrict__ x1,
                                                  const float* __restrict__ yl1,
                                                  const float* __restrict__ yl2,
                                                  const float* __restrict__ x2c,
                                                  const float* __restrict__ lnG,
                                                  const float* __restrict__ lnB,
                                                  unsigned short* __restrict__ hbf,
                                                  int do_relu) {
    int t    = threadIdx.x;
    int blk  = blockIdx.x;                 // 8192 = 2 * 256 * 16
    int b    = blk >> 12;
    int rest = blk & 4095;
    int y    = rest >> 4;
    int x0   = (rest & 15) << 4;
    int wv = t >> 6, lane = t & 63;

    float g = lnG[lane], be = lnB[lane];
    const float* Y1 = yl1 + (size_t)b * 16384 * 64;
    const float* Y2 = yl2 + (size_t)b * 4096 * 64;
    const float* XC = x2c + (size_t)b * 16384 * 64;

    for (int pp = 0; pp < 4; ++pp) {
        int xx = x0 + wv * 4 + pp;
        size_t pix = (size_t)((b * 256 + y) * 256 + xx);
        float v = x1[pix * 64 + lane];
        {
            Lerp ly = lcoord(y, 0.5f, -0.25f, 128);
            Lerp lx = lcoord(xx, 0.5f, -0.25f, 128);
            v += bilerp64(Y1, 128, ly, lx, lane);
        }
        {
            Lerp ly = lcoord(y, 0.25f, -0.375f, 64);
            Lerp lx = lcoord(xx, 0.25f, -0.375f, 64);
            v += bilerp64(Y2, 64, ly, lx, lane);
        }
        {
            Lerp ly = lcoord(y, 0.5f, -0.25f, 128);
            Lerp lx = lcoord(xx, 0.5f, -0.25f, 128);
            v += bilerp64(XC, 128, ly, lx, lane);
        }
        float mu  = wave_sum64(v) * (1.f / 64.f);
        float d   = v - mu;
        float var = wave_sum64(d * d) * (1.f / 64.f);
        float ov  = fmaf(d * rsqrtf(var + 1e-5f), g, be);
        if (do_relu) ov = fmaxf(ov, 0.f);
        hbf[pix * 64 + lane] = f2bf(ov);
    }
}

// ---------------- head (MFMA): out = relu(hbf@q1W+q1b) . q2 + q2b ----------------
__global__ __launch_bounds__(256) void k_head_mfma(
    const unsigned short* __restrict__ hbf,   // [131072][64] bf16
    const unsigned short* __restrict__ q1bf,  // [128 j][64 k] bf16
    const float* __restrict__ q1b,            // [128]
    const float* __restrict__ q2,             // [128]
    const float* __restrict__ q2b,            // [1]
    float* __restrict__ out) {
    __shared__ unsigned short Q[8192];        // [j][k] swizzled
    int t = threadIdx.x;
    for (int c = t; c < 1024; c += 256) {
        int j = c >> 3, slot = c & 7;
        uint4 v = *(const uint4*)(q1bf + j * 64 + slot * 8);
        int byte = (j * 128 + slot * 16) ^ ((j & 7) << 4);
        *(uint4*)((char*)Q + byte) = v;
    }
    __syncthreads();

    int w = t >> 6, lane = t & 63;
    int lo = lane & 31, hi = lane >> 5;
    int px0 = blockIdx.x * 128 + w * 32;      // grid 1024

    bf16x8_t av[4];
    const unsigned short* hp = hbf + (size_t)(px0 + lo) * 64 + hi * 8;
#pragma unroll
    for (int ks = 0; ks < 4; ++ks)
        av[ks] = *(const bf16x8_t*)(hp + ks * 16);

    float res[16];
#pragma unroll
    for (int r = 0; r < 16; ++r) res[r] = 0.f;

#pragma unroll
    for (int jb = 0; jb < 4; ++jb) {
        f32x16_t acc = {};
        int j = jb * 32 + lo;
#pragma unroll
        for (int ks = 0; ks < 4; ++ks) {
            int byte = (j * 128 + ks * 32 + hi * 16) ^ ((j & 7) << 4);
            bf16x8_t bv = *(bf16x8_t*)((char*)Q + byte);
            acc = __builtin_amdgcn_mfma_f32_32x32x16_bf16(av[ks], bv, acc, 0, 0, 0);
        }
        float b1 = q1b[j];
        float w2 = q2[j];
#pragma unroll
        for (int r = 0; r < 16; ++r)
            res[r] = fmaf(fmaxf(acc[r] + b1, 0.f), w2, res[r]);
    }
#pragma unroll
    for (int r = 0; r < 16; ++r) {
        float v = res[r];
        v += __shfl_xor(v, 1);
        v += __shfl_xor(v, 2);
        v += __shfl_xor(v, 4);
        v += __shfl_xor(v, 8);
        v += __shfl_xor(v, 16);
        res[r] = v;
    }
    if (lo == 0) {
        float qb = q2b[0];
#pragma unroll
        for (int r = 0; r < 16; ++r) {
            int row = (r & 3) + 8 * (r >> 2) + 4 * hi;
            out[px0 + row] = res[r] + qb;
        }
    }
}

// ---------------- launch ----------------
extern "C" void kernel_launch(void* const* d_in, const int* in_sizes, int n_in,
                              void* d_out, int out_size, void* d_ws, size_t ws_size,
                              hipStream_t stream) {
    const float* x     = (const float*)d_in[0];
    const float* a     = (const float*)d_in[1];
    const float* pW    = (const float*)d_in[2];
    const float* pb    = (const float*)d_in[3];
    const float* q1W   = (const float*)d_in[4];
    const float* q1b   = (const float*)d_in[5];
    const float* q2W   = (const float*)d_in[6];
    const float* q2b   = (const float*)d_in[7];
    const float* phiW1 = (const float*)d_in[8];
    const float* phib1 = (const float*)d_in[9];
    const float* phiW2 = (const float*)d_in[10];
    const float* phib2 = (const float*)d_in[11];
    const float* phiW3 = (const float*)d_in[12];
    const float* phib3 = (const float*)d_in[13];
    const float* psiW1 = (const float*)d_in[14];
    const float* psib1 = (const float*)d_in[15];
    const float* psiW2 = (const float*)d_in[16];
    const float* psib2 = (const float*)d_in[17];
    const float* psiW3 = (const float*)d_in[18];
    const float* psib3 = (const float*)d_in[19];
    const float* lnG   = (const float*)d_in[20];
    const float* lnB   = (const float*)d_in[21];
    const float* convW = (const float*)d_in[22];
    const float* convb = (const float*)d_in[23];

    float* ws    = (float*)d_ws;
    float* x1    = ws + OFF_X1;
    float* yl1   = ws + OFF_YL1;
    float* yl2   = ws + OFF_YL2;
    unsigned short* hbf = (unsigned short*)(ws + OFF_HBF);
    float* H2phi = ws + OFF_H2PHI;
    float* x2c   = ws + OFF_X2C;
    unsigned short* cwtbf = (unsigned short*)(ws + OFF_CWTBF);
    unsigned short* q1bf  = (unsigned short*)(ws + OFF_Q1BF);
    float* Gpart = ws + OFF_GPART;
    float* svpart= ws + OFF_SVP;
    float* G     = ws + OFF_G;
    float* sv    = ws + OFF_SV;

    k_transpose_convw_bf<<<1728, 256, 0, stream>>>(convW, cwtbf);
    k_transpose_q1bf<<<32, 256, 0, stream>>>(q1W, q1bf);

    k_lift<<<512, 256, 0, stream>>>(x, a, pW, pb, hbf);

    for (int i = 0; i < 4; ++i) {
        k_conv_mfma<<<1344, 256, 0, stream>>>(hbf, cwtbf, convb, x1, yl1, yl2, i);
        k_mlpg<<<512, 256, 0, stream>>>(a, x,
                                        psiW1 + i * 192, psib1 + i * 64,
                                        psiW2 + i * 8192, psib2 + i * 128,
                                        phiW1 + i * 192, phib1 + i * 64,
                                        phiW2 + i * 8192, phib2 + i * 128,
                                        hbf, H2phi, Gpart, svpart);
        k_gred<<<258, 256, 0, stream>>>(Gpart, svpart, G, sv);
        k_x2cyc<<<128, 256, 0, stream>>>(G, sv,
                                         psiW3 + (size_t)i * 32768, psib3 + i * 256,
                                         phiW3 + (size_t)i * 32768, phib3 + i * 256,
                                         H2phi, x2c);
        k_epilogue<<<8192, 256, 0, stream>>>(x1, yl1, yl2, x2c,
                                             lnG + i * 64, lnB + i * 64,
                                             hbf, (i < 3) ? 1 : 0);
    }

    k_head_mfma<<<1024, 256, 0, stream>>>(hbf, q1bf, q1b, q2W, q2b, (float*)d_out);
}

// Round 7
// 637.019 us; speedup vs baseline: 1.1438x; 1.1438x over previous
//
#include <hip/hip_runtime.h>
#include <cstddef>
#include <cstdint>

// ---------------- problem constants ----------------
// b=2, s=256, WIDTH=64, RANK=4, CLEVEL=1 (c=2), MLEVEL=2 (L=3), NB=4
// HID1=64, HID2=128

// ---------------- workspace layout (float offsets) ----------------
static constexpr size_t OFF_X1     = 0;          // 8388608
static constexpr size_t OFF_YL1    = 8388608;    // 2097152
static constexpr size_t OFF_YL2    = 10485760;   // 524288
static constexpr size_t OFF_HBF    = 11010048;   // bf16 h: 8388608 bf16 = 4194304 slots
static constexpr size_t OFF_H2PSI  = 15204352;   // 4194304 (x2c overlays after k_gpart)
static constexpr size_t OFF_H2PHI  = 19398656;   // 4194304
static constexpr size_t OFF_CWTBF  = 23592960;   // 221184
static constexpr size_t OFF_Q1BF   = 23814144;   // 4096
static constexpr size_t OFF_GPART  = 23818240;   // 512*8192 = 4194304
static constexpr size_t OFF_SVP    = 28012544;   // 512*64 = 32768
static constexpr size_t OFF_G      = 28045312;   // 16384
static constexpr size_t OFF_SV     = 28061696;   // 128
// end = 28061824 floats (~112 MB) <= proven-available 134.3 MB

typedef __attribute__((ext_vector_type(8)))  short bf16x8_t;   // 8 bf16 in 4 VGPRs
typedef __attribute__((ext_vector_type(16))) float f32x16_t;   // 32x32 MFMA acc

// ---------------- helpers ----------------
__device__ inline float wave_sum64(float v) {
    v += __shfl_xor(v, 1);
    v += __shfl_xor(v, 2);
    v += __shfl_xor(v, 4);
    v += __shfl_xor(v, 8);
    v += __shfl_xor(v, 16);
    v += __shfl_xor(v, 32);
    return v;
}

__device__ inline unsigned short f2bf(float f) {   // round-to-nearest-even
    uint32_t u = __float_as_uint(f);
    uint32_t r = u + 0x7FFFu + ((u >> 16) & 1u);
    return (unsigned short)(r >> 16);
}

// full-res flat pixel index of coarse pixel (b, n): n in [0,16384)
__device__ inline size_t fullpix(int b, int n) {
    return (size_t)(b * 65536 + (n >> 7) * 512 + ((n & 127) << 1));
}

struct Lerp { int i0, i1; float f; };
__device__ inline Lerp lcoord(int o, float r, float off, int Sin) {
    float s = fmaxf(fmaf((float)o, r, off), 0.f);
    Lerp L;
    L.i0 = (int)s;
    L.f  = s - (float)L.i0;
    L.i1 = min(L.i0 + 1, Sin - 1);
    return L;
}
__device__ inline float bilerp64(const float* __restrict__ base, int Sin,
                                 const Lerp& ly, const Lerp& lx, int lane) {
    float v00 = base[((size_t)(ly.i0 * Sin + lx.i0)) * 64 + lane];
    float v01 = base[((size_t)(ly.i0 * Sin + lx.i1)) * 64 + lane];
    float v10 = base[((size_t)(ly.i1 * Sin + lx.i0)) * 64 + lane];
    float v11 = base[((size_t)(ly.i1 * Sin + lx.i1)) * 64 + lane];
    float a = v00 + lx.f * (v01 - v00);
    float b = v10 + lx.f * (v11 - v10);
    return a + ly.f * (b - a);
}

// ---------------- weight transforms ----------------
// convW[i][l][oc][ic][3][3] f32 -> cwtbf[i*3+l][oc][tap*64+ic] bf16
__global__ __launch_bounds__(256) void k_transpose_convw_bf(const float* __restrict__ w,
                                                            unsigned short* __restrict__ wt) {
    int idx = blockIdx.x * 256 + threadIdx.x;     // 12*64*576 = 442368
    if (idx >= 442368) return;
    int k    = idx % 576;
    int rest = idx / 576;
    int oc   = rest & 63;
    int il   = rest >> 6;
    int tap  = k >> 6;
    int ic   = k & 63;
    wt[idx] = f2bf(w[((size_t)(il * 64 + oc) * 64 + ic) * 9 + tap]);
}
// q1W[64][128] f32 -> q1bf[j][k] bf16 (transposed)
__global__ __launch_bounds__(256) void k_transpose_q1bf(const float* __restrict__ w,
                                                        unsigned short* __restrict__ wt) {
    int idx = blockIdx.x * 256 + threadIdx.x;     // 8192
    if (idx >= 8192) return;
    int k = idx & 63;
    int j = idx >> 6;
    wt[j * 64 + k] = f2bf(w[k * 128 + j]);
}

// ---------------- lift: h = [a0,a1,x] @ pW + pb (writes bf16 NHWC) ----------------
__global__ __launch_bounds__(256) void k_lift(const float* __restrict__ x,
                                              const float* __restrict__ a,
                                              const float* __restrict__ pW,
                                              const float* __restrict__ pb,
                                              unsigned short* __restrict__ hbf) {
    int p = blockIdx.x * 256 + threadIdx.x;       // 131072
    float a0 = a[(size_t)p * 2 + 0];
    float a1 = a[(size_t)p * 2 + 1];
    float xv = x[p];
    float vals[64];
#pragma unroll
    for (int c = 0; c < 64; ++c)
        vals[c] = fmaf(a0, pW[c], fmaf(a1, pW[64 + c], fmaf(xv, pW[128 + c], pb[c])));
    unsigned short us[64];
#pragma unroll
    for (int c = 0; c < 64; ++c) us[c] = f2bf(vals[c]);
    unsigned short* bp = hbf + (size_t)p * 64;
#pragma unroll
    for (int c = 0; c < 64; c += 8)
        *(uint4*)(bp + c) = *(uint4*)(us + c);
}

// ---------------- MFMA conv 3x3 SAME (64->64), oc-split for 2 blocks/CU ----------------
// Each block: 16x16 px tile x 32 output channels. Grid 1344.
__global__ __launch_bounds__(256) void k_conv_mfma(
    const unsigned short* __restrict__ hbf,   // [2][256][256][64] bf16
    const unsigned short* __restrict__ wbf,   // [12][64][576] bf16
    const float* __restrict__ convb,          // [12][64]
    float* __restrict__ x1, float* __restrict__ yl1, float* __restrict__ yl2,
    int iter) {
    __shared__ unsigned short Ald[20736];     // 324 px * 64 ic  (41472 B)
    __shared__ unsigned short Bld[18432];     // 32 oc * 576 k   (36864 B)

    int bid = blockIdx.x;
    int lvl, q2_, Sl, st, tpr;
    if (bid < 1024)      { lvl = 0; q2_ = bid;        Sl = 256; st = 1; tpr = 16; }
    else if (bid < 1280) { lvl = 1; q2_ = bid - 1024; Sl = 128; st = 2; tpr = 8;  }
    else                 { lvl = 2; q2_ = bid - 1280; Sl = 64;  st = 4; tpr = 4;  }
    int tix = q2_ >> 1;
    int oc0 = (q2_ & 1) << 5;
    int tpb = tpr * tpr;
    int b = tix / tpb;
    int r = tix - b * tpb;
    int y0 = (r / tpr) * 16, x0 = (r % tpr) * 16;
    int t = threadIdx.x;

    // ---- stage A: 18x18 halo x 64 ic, zero-padded at image edges ----
    for (int c = t; c < 2592; c += 256) {       // 324 rows * 8 slots(16B)
        int lin = c >> 3, slot = c & 7;
        int ty = lin / 18, tx = lin - ty * 18;
        int oy = y0 + ty - 1, ox = x0 + tx - 1;
        uint4 val = make_uint4(0u, 0u, 0u, 0u);
        if ((unsigned)oy < (unsigned)Sl && (unsigned)ox < (unsigned)Sl) {
            const unsigned short* src =
                hbf + (((size_t)(b * 256 + oy * st) * 256 + ox * st) << 6) + (slot << 3);
            val = *(const uint4*)src;
        }
        int byte = (lin << 7) + (((slot ^ (lin & 7))) << 4);
        *(uint4*)((char*)Ald + byte) = val;
    }
    // ---- stage B: 32 oc rows of weights for this (iter,lvl,oc0) ----
    {
        const unsigned short* wsrc = wbf + (size_t)(iter * 3 + lvl) * 36864 + (size_t)oc0 * 576;
        int ocl = t >> 3, q = t & 7;
#pragma unroll
        for (int j = 0; j < 18; ++j) {
            int ke = q * 72 + j * 4;                    // bf16 elems
            uint2 v = *(const uint2*)(wsrc + ocl * 576 + ke);
            int byte = (ocl * 1152 + (ke << 1)) ^ ((ocl & 7) << 4);
            *(uint2*)((char*)Bld + byte) = v;
        }
    }
    __syncthreads();

    // ---- compute ----
    int w    = t >> 6;
    int lane = t & 63;
    int lo   = lane & 31;
    int hi   = lane >> 5;
    f32x16_t acc00 = {}, acc10 = {};

    int yA0 = 4 * w + (lo >> 4);
    int xA  = lo & 15;
#pragma unroll 3
    for (int tap = 0; tap < 9; ++tap) {
        int dy = tap / 3, dx = tap - dy * 3;
        int lin0 = (yA0 + dy) * 18 + (xA + dx);
        int lin1 = lin0 + 36;
#pragma unroll
        for (int kq = 0; kq < 4; ++kq) {
            int icb = (kq << 5) + (hi << 4);
            int a0b = ((lin0 << 7) + icb) ^ ((lin0 & 7) << 4);
            int a1b = ((lin1 << 7) + icb) ^ ((lin1 & 7) << 4);
            bf16x8_t va0 = *(bf16x8_t*)((char*)Ald + a0b);
            bf16x8_t va1 = *(bf16x8_t*)((char*)Ald + a1b);
            int kk  = tap * 128 + icb;
            int b0b = (lo * 1152 + kk) ^ ((lo & 7) << 4);
            bf16x8_t vb0 = *(bf16x8_t*)((char*)Bld + b0b);
            acc00 = __builtin_amdgcn_mfma_f32_32x32x16_bf16(va0, vb0, acc00, 0, 0, 0);
            acc10 = __builtin_amdgcn_mfma_f32_32x32x16_bf16(va1, vb0, acc10, 0, 0, 0);
        }
    }

    // ---- store ----
    float* out = (lvl == 0) ? x1 : (lvl == 1 ? yl1 : yl2);
    float bias0 = convb[(iter * 3 + lvl) * 64 + oc0 + lo];
#pragma unroll
    for (int reg = 0; reg < 16; ++reg) {
        int row = (reg & 3) + 8 * (reg >> 2) + 4 * hi;
        int yt  = 4 * w + (row >> 4);
        int xt  = row & 15;
        size_t pix0 = ((size_t)(b * Sl + y0 + yt) * Sl + (x0 + xt)) << 6;
        out[pix0 + oc0 + lo] = acc00[reg] + bias0;
        size_t pix1 = ((size_t)(b * Sl + y0 + yt + 2) * Sl + (x0 + xt)) << 6;
        out[pix1 + oc0 + lo] = acc10[reg] + bias0;
    }
}

// ---------------- mlp12: H2 = relu(relu(a@W1+b1)@W2+b2), 4 threads/px ----------------
__global__ __launch_bounds__(256) void k_mlp12(
    const float* __restrict__ a, const float* __restrict__ x,
    const float* __restrict__ W1a, const float* __restrict__ b1a,
    const float* __restrict__ W2a, const float* __restrict__ b2a,
    const float* __restrict__ W1b, const float* __restrict__ b1b,
    const float* __restrict__ W2b, const float* __restrict__ b2b,
    float* __restrict__ H2a, float* __restrict__ H2b) {
    int blk = blockIdx.x;                          // 1024
    int m = blk >> 9;
    int t = threadIdx.x;
    int pxl = ((blk & 511) << 6) | (t & 63);       // 0..32767
    int j0 = __builtin_amdgcn_readfirstlane((t >> 6) << 5);  // 0/32/64/96
    const float* W1 = m ? W1b : W1a;
    const float* b1 = m ? b1b : b1a;
    const float* W2 = m ? W2b : W2a;
    const float* b2 = m ? b2b : b2a;
    float* H2 = m ? H2b : H2a;
    int b = pxl >> 14, n = pxl & 16383;
    size_t apix = fullpix(b, n);
    float a0 = a[apix * 2], a1 = a[apix * 2 + 1], xv = x[apix];

    float acc[32];
#pragma unroll
    for (int j = 0; j < 32; ++j) acc[j] = b2[j0 + j];
#pragma unroll 1
    for (int k = 0; k < 64; ++k) {
        float h1 = fmaxf(fmaf(a0, W1[k], fmaf(a1, W1[64 + k], fmaf(xv, W1[128 + k], b1[k]))), 0.f);
        const float* wr = W2 + k * 128 + j0;
#pragma unroll
        for (int j = 0; j < 32; ++j) acc[j] = fmaf(h1, wr[j], acc[j]);
    }
    float* op = H2 + (size_t)pxl * 128 + j0;
#pragma unroll
    for (int j = 0; j < 32; j += 4)
        *(float4*)(op + j) = make_float4(fmaxf(acc[j], 0.f), fmaxf(acc[j + 1], 0.f),
                                         fmaxf(acc[j + 2], 0.f), fmaxf(acc[j + 3], 0.f));
}

// ---------------- split-K stage 1: Gpart[blk] = v^T H2psi over 64 px; svpart ----------------
// LDS tiles XOR-swizzled (byte ^= (px&7)<<4): staging stores and reads both <=2-way.
__global__ __launch_bounds__(256) void k_gpart(const unsigned short* __restrict__ hbf,
                                               const float* __restrict__ H2psi,
                                               float* __restrict__ Gpart,
                                               float* __restrict__ svpart) {
    __shared__ float vt[4096];       // [64 px][64 w]
    __shared__ float h2t[8192];      // [64 px][128 j]
    int blk = blockIdx.x;            // 512
    int b = blk >> 8;
    int n0 = (blk & 255) << 6;
    int t = threadIdx.x;
    int pxq = t >> 2, qq = t & 3;
    int sw = (pxq & 7) << 4;
    {
        const unsigned short* src = hbf + fullpix(b, n0 + pxq) * 64 + qq * 16;
        uint4 u0 = *(const uint4*)src;
        uint4 u1 = *(const uint4*)(src + 8);
        unsigned uv[8] = {u0.x, u0.y, u0.z, u0.w, u1.x, u1.y, u1.z, u1.w};
        float f[16];
#pragma unroll
        for (int i = 0; i < 8; ++i) {
            f[2 * i]     = __uint_as_float((uv[i] & 0xFFFFu) << 16);
            f[2 * i + 1] = __uint_as_float(uv[i] & 0xFFFF0000u);
        }
#pragma unroll
        for (int j = 0; j < 4; ++j) {
            int byte = (pxq * 256 + qq * 64 + j * 16) ^ sw;
            *(float4*)((char*)vt + byte) = make_float4(f[4 * j], f[4 * j + 1],
                                                       f[4 * j + 2], f[4 * j + 3]);
        }
        const float* hsrc = &H2psi[((size_t)(b * 16384 + n0 + pxq)) * 128 + qq * 32];
#pragma unroll
        for (int rr = 0; rr < 8; ++rr) {
            int byte = (pxq * 512 + qq * 128 + rr * 16) ^ sw;
            *(float4*)((char*)h2t + byte) = *(const float4*)(hsrc + rr * 4);
        }
    }
    __syncthreads();

    int wt_ = (t >> 5) << 3;         // 0..56
    int kt  = (t & 31) << 2;         // 0..124
    float acc[8][4];
#pragma unroll
    for (int i = 0; i < 8; ++i)
#pragma unroll
        for (int j = 0; j < 4; ++j) acc[i][j] = 0.f;

#pragma unroll 4
    for (int nn = 0; nn < 64; ++nn) {
        int nsw = (nn & 7) << 4;
        float4 hv = *(float4*)((char*)h2t + ((nn * 512 + kt * 4) ^ nsw));
        float4 v0 = *(float4*)((char*)vt + ((nn * 256 + wt_ * 4) ^ nsw));
        float4 v1 = *(float4*)((char*)vt + ((nn * 256 + wt_ * 4 + 16) ^ nsw));
        float vv[8] = {v0.x, v0.y, v0.z, v0.w, v1.x, v1.y, v1.z, v1.w};
        float hh[4] = {hv.x, hv.y, hv.z, hv.w};
#pragma unroll
        for (int i = 0; i < 8; ++i)
#pragma unroll
            for (int j = 0; j < 4; ++j) acc[i][j] = fmaf(vv[i], hh[j], acc[i][j]);
    }

    float* gp = Gpart + (size_t)blk * 8192;
#pragma unroll
    for (int i = 0; i < 8; ++i)
        *(float4*)&gp[(wt_ + i) * 128 + kt] =
            make_float4(acc[i][0], acc[i][1], acc[i][2], acc[i][3]);

    if (t < 64) {
        float s = 0.f;
#pragma unroll 8
        for (int p = 0; p < 64; ++p)
            s += *(float*)((char*)vt + ((p * 256 + t * 4) ^ ((p & 7) << 4)));
        svpart[blk * 64 + t] = s;
    }
}

// ---------------- reduce: G = sum Gpart; sv = sum svpart (grid 258) ----------------
__global__ __launch_bounds__(256) void k_gred(const float* __restrict__ Gpart,
                                              const float* __restrict__ svpart,
                                              float* __restrict__ G,
                                              float* __restrict__ sv) {
    __shared__ float red[4][64];
    int blk = blockIdx.x;
    int t = threadIdx.x;
    if (blk < 256) {
        int b  = blk >> 7;
        int es = (blk & 127) << 6;
        int e  = es + (t & 63);
        int cg = t >> 6;
        float s = 0.f;
        const float* gp = Gpart + ((size_t)(b * 256 + cg * 64)) * 8192 + e;
#pragma unroll 8
        for (int c = 0; c < 64; ++c) s += gp[(size_t)c * 8192];
        red[cg][t & 63] = s;
        __syncthreads();
        if (t < 64)
            G[b * 8192 + es + t] = red[0][t] + red[1][t] + red[2][t] + red[3][t];
    } else {
        int b = blk - 256;
        int w = t & 63, cg = t >> 6;
        float s = 0.f;
        const float* sp = svpart + ((size_t)(b * 256 + cg * 64)) * 64 + w;
#pragma unroll 8
        for (int c = 0; c < 64; ++c) s += sp[c * 64];
        red[cg][w] = s;
        __syncthreads();
        if (t < 64) sv[b * 64 + t] = red[0][t] + red[1][t] + red[2][t] + red[3][t];
    }
}

// ---------------- fused yc + x2c: ybar,C,D in LDS, then x2c GEMM ----------------
__global__ __launch_bounds__(256) void k_x2cyc(const float* __restrict__ G,
                                               const float* __restrict__ sv,
                                               const float* __restrict__ W3psi,
                                               const float* __restrict__ b3psi,
                                               const float* __restrict__ W3phi,
                                               const float* __restrict__ b3phi,
                                               const float* __restrict__ H2phi,
                                               float* __restrict__ x2c) {
    __shared__ float ybar[256];
    __shared__ float cl[8192];
    __shared__ float Dl[64];
    int blk = blockIdx.x;            // 128
    int b = blk >> 6;
    int px0 = blk << 8;
    int t = threadIdx.x;

    {   // ybar (redundant per block; 32K FMA)
        int o = t, w = o >> 2;
        float s = b3psi[o] * sv[b * 64 + w];
        const float* gp = &G[(size_t)(b * 64 + w) * 128];
#pragma unroll 4
        for (int k = 0; k < 128; ++k) s = fmaf(W3psi[k * 256 + o], gp[k], s);
        ybar[o] = s * (1.f / 16384.f);
    }
    __syncthreads();
#pragma unroll
    for (int rep = 0; rep < 32; ++rep) {
        int e = rep * 256 + t;       // C: 8192 elems
        int w = e >> 7, k = e & 127;
        const float* wp = &W3phi[k * 256 + w * 4];
        cl[e] = fmaf(wp[0], ybar[w * 4],
                fmaf(wp[1], ybar[w * 4 + 1],
                fmaf(wp[2], ybar[w * 4 + 2], wp[3] * ybar[w * 4 + 3])));
    }
    if (t < 64) {
        Dl[t] = b3phi[t * 4] * ybar[t * 4] + b3phi[t * 4 + 1] * ybar[t * 4 + 1]
              + b3phi[t * 4 + 2] * ybar[t * 4 + 2] + b3phi[t * 4 + 3] * ybar[t * 4 + 3];
    }
    __syncthreads();

    int w0 = __builtin_amdgcn_readfirstlane((t >> 6) << 4);
    int px = px0 + ((t & 63) << 2);
    float acc[4][16];
#pragma unroll
    for (int i = 0; i < 4; ++i)
#pragma unroll
        for (int j = 0; j < 16; ++j) acc[i][j] = 0.f;

    const float* hbase = H2phi + (size_t)px * 128;
#pragma unroll 2
    for (int kq = 0; kq < 32; ++kq) {
        float4 h2q[4];
#pragma unroll
        for (int i = 0; i < 4; ++i) h2q[i] = *(const float4*)&hbase[i * 128 + kq * 4];
#pragma unroll
        for (int j = 0; j < 16; ++j) {
            float4 cq = *(float4*)&cl[(w0 + j) * 128 + kq * 4];
#pragma unroll
            for (int i = 0; i < 4; ++i) {
                acc[i][j] = fmaf(h2q[i].x, cq.x, acc[i][j]);
                acc[i][j] = fmaf(h2q[i].y, cq.y, acc[i][j]);
                acc[i][j] = fmaf(h2q[i].z, cq.z, acc[i][j]);
                acc[i][j] = fmaf(h2q[i].w, cq.w, acc[i][j]);
            }
        }
    }
#pragma unroll
    for (int i = 0; i < 4; ++i) {
        float* op = &x2c[(size_t)(px + i) * 64 + w0];
#pragma unroll
        for (int j = 0; j < 16; j += 4) {
            float4 o4 = make_float4(acc[i][j]     + Dl[w0 + j],
                                    acc[i][j + 1] + Dl[w0 + j + 1],
                                    acc[i][j + 2] + Dl[w0 + j + 2],
                                    acc[i][j + 3] + Dl[w0 + j + 3]);
            *(float4*)(op + j) = o4;
        }
    }
}

// ---------------- epilogue: h = LN(x1 + up(yl1) + up(yl2) + up(x2c)); writes bf16 ----------------
__global__ __launch_bounds__(256) void k_epilogue(const float* __restrict__ x1,
                                                  const float* __restrict__ yl1,
                                                  const float* __restrict__ yl2,
                                                  const float* __restrict__ x2c,
                                                  const float* __restrict__ lnG,
                                                  const float* __restrict__ lnB,
                                                  unsigned short* __restrict__ hbf,
                                                  int do_relu) {
    int t    = threadIdx.x;
    int blk  = blockIdx.x;                 // 8192 = 2 * 256 * 16
    int b    = blk >> 12;
    int rest = blk & 4095;
    int y    = rest >> 4;
    int x0   = (rest & 15) << 4;
    int wv = t >> 6, lane = t & 63;

    float g = lnG[lane], be = lnB[lane];
    const float* Y1 = yl1 + (size_t)b * 16384 * 64;
    const float* Y2 = yl2 + (size_t)b * 4096 * 64;
    const float* XC = x2c + (size_t)b * 16384 * 64;

    for (int pp = 0; pp < 4; ++pp) {
        int xx = x0 + wv * 4 + pp;
        size_t pix = (size_t)((b * 256 + y) * 256 + xx);
        float v = x1[pix * 64 + lane];
        {
            Lerp ly = lcoord(y, 0.5f, -0.25f, 128);
            Lerp lx = lcoord(xx, 0.5f, -0.25f, 128);
            v += bilerp64(Y1, 128, ly, lx, lane);
        }
        {
            Lerp ly = lcoord(y, 0.25f, -0.375f, 64);
            Lerp lx = lcoord(xx, 0.25f, -0.375f, 64);
            v += bilerp64(Y2, 64, ly, lx, lane);
        }
        {
            Lerp ly = lcoord(y, 0.5f, -0.25f, 128);
            Lerp lx = lcoord(xx, 0.5f, -0.25f, 128);
            v += bilerp64(XC, 128, ly, lx, lane);
        }
        float mu  = wave_sum64(v) * (1.f / 64.f);
        float d   = v - mu;
        float var = wave_sum64(d * d) * (1.f / 64.f);
        float ov  = fmaf(d * rsqrtf(var + 1e-5f), g, be);
        if (do_relu) ov = fmaxf(ov, 0.f);
        hbf[pix * 64 + lane] = f2bf(ov);
    }
}

// ---------------- head (MFMA): out = relu(hbf@q1W+q1b) . q2 + q2b ----------------
__global__ __launch_bounds__(256) void k_head_mfma(
    const unsigned short* __restrict__ hbf,   // [131072][64] bf16
    const unsigned short* __restrict__ q1bf,  // [128 j][64 k] bf16
    const float* __restrict__ q1b,            // [128]
    const float* __restrict__ q2,             // [128]
    const float* __restrict__ q2b,            // [1]
    float* __restrict__ out) {
    __shared__ unsigned short Q[8192];        // [j][k] swizzled
    int t = threadIdx.x;
    for (int c = t; c < 1024; c += 256) {
        int j = c >> 3, slot = c & 7;
        uint4 v = *(const uint4*)(q1bf + j * 64 + slot * 8);
        int byte = (j * 128 + slot * 16) ^ ((j & 7) << 4);
        *(uint4*)((char*)Q + byte) = v;
    }
    __syncthreads();

    int w = t >> 6, lane = t & 63;
    int lo = lane & 31, hi = lane >> 5;
    int px0 = blockIdx.x * 128 + w * 32;      // grid 1024

    bf16x8_t av[4];
    const unsigned short* hp = hbf + (size_t)(px0 + lo) * 64 + hi * 8;
#pragma unroll
    for (int ks = 0; ks < 4; ++ks)
        av[ks] = *(const bf16x8_t*)(hp + ks * 16);

    float res[16];
#pragma unroll
    for (int r = 0; r < 16; ++r) res[r] = 0.f;

#pragma unroll
    for (int jb = 0; jb < 4; ++jb) {
        f32x16_t acc = {};
        int j = jb * 32 + lo;
#pragma unroll
        for (int ks = 0; ks < 4; ++ks) {
            int byte = (j * 128 + ks * 32 + hi * 16) ^ ((j & 7) << 4);
            bf16x8_t bv = *(bf16x8_t*)((char*)Q + byte);
            acc = __builtin_amdgcn_mfma_f32_32x32x16_bf16(av[ks], bv, acc, 0, 0, 0);
        }
        float b1 = q1b[j];
        float w2 = q2[j];
#pragma unroll
        for (int r = 0; r < 16; ++r)
            res[r] = fmaf(fmaxf(acc[r] + b1, 0.f), w2, res[r]);
    }
#pragma unroll
    for (int r = 0; r < 16; ++r) {
        float v = res[r];
        v += __shfl_xor(v, 1);
        v += __shfl_xor(v, 2);
        v += __shfl_xor(v, 4);
        v += __shfl_xor(v, 8);
        v += __shfl_xor(v, 16);
        res[r] = v;
    }
    if (lo == 0) {
        float qb = q2b[0];
#pragma unroll
        for (int r = 0; r < 16; ++r) {
            int row = (r & 3) + 8 * (r >> 2) + 4 * hi;
            out[px0 + row] = res[r] + qb;
        }
    }
}

// ---------------- launch ----------------
extern "C" void kernel_launch(void* const* d_in, const int* in_sizes, int n_in,
                              void* d_out, int out_size, void* d_ws, size_t ws_size,
                              hipStream_t stream) {
    const float* x     = (const float*)d_in[0];
    const float* a     = (const float*)d_in[1];
    const float* pW    = (const float*)d_in[2];
    const float* pb    = (const float*)d_in[3];
    const float* q1W   = (const float*)d_in[4];
    const float* q1b   = (const float*)d_in[5];
    const float* q2W   = (const float*)d_in[6];
    const float* q2b   = (const float*)d_in[7];
    const float* phiW1 = (const float*)d_in[8];
    const float* phib1 = (const float*)d_in[9];
    const float* phiW2 = (const float*)d_in[10];
    const float* phib2 = (const float*)d_in[11];
    const float* phiW3 = (const float*)d_in[12];
    const float* phib3 = (const float*)d_in[13];
    const float* psiW1 = (const float*)d_in[14];
    const float* psib1 = (const float*)d_in[15];
    const float* psiW2 = (const float*)d_in[16];
    const float* psib2 = (const float*)d_in[17];
    const float* psiW3 = (const float*)d_in[18];
    const float* psib3 = (const float*)d_in[19];
    const float* lnG   = (const float*)d_in[20];
    const float* lnB   = (const float*)d_in[21];
    const float* convW = (const float*)d_in[22];
    const float* convb = (const float*)d_in[23];

    float* ws    = (float*)d_ws;
    float* x1    = ws + OFF_X1;
    float* yl1   = ws + OFF_YL1;
    float* yl2   = ws + OFF_YL2;
    unsigned short* hbf = (unsigned short*)(ws + OFF_HBF);
    float* H2psi = ws + OFF_H2PSI;
    float* x2c   = ws + OFF_H2PSI;            // overlay: H2psi dead after k_gpart
    float* H2phi = ws + OFF_H2PHI;
    unsigned short* cwtbf = (unsigned short*)(ws + OFF_CWTBF);
    unsigned short* q1bf  = (unsigned short*)(ws + OFF_Q1BF);
    float* Gpart = ws + OFF_GPART;
    float* svpart= ws + OFF_SVP;
    float* G     = ws + OFF_G;
    float* sv    = ws + OFF_SV;

    k_transpose_convw_bf<<<1728, 256, 0, stream>>>(convW, cwtbf);
    k_transpose_q1bf<<<32, 256, 0, stream>>>(q1W, q1bf);

    k_lift<<<512, 256, 0, stream>>>(x, a, pW, pb, hbf);

    for (int i = 0; i < 4; ++i) {
        k_conv_mfma<<<1344, 256, 0, stream>>>(hbf, cwtbf, convb, x1, yl1, yl2, i);
        k_mlp12<<<1024, 256, 0, stream>>>(a, x,
                                          psiW1 + i * 192, psib1 + i * 64,
                                          psiW2 + i * 8192, psib2 + i * 128,
                                          phiW1 + i * 192, phib1 + i * 64,
                                          phiW2 + i * 8192, phib2 + i * 128,
                                          H2psi, H2phi);
        k_gpart<<<512, 256, 0, stream>>>(hbf, H2psi, Gpart, svpart);
        k_gred<<<258, 256, 0, stream>>>(Gpart, svpart, G, sv);
        k_x2cyc<<<128, 256, 0, stream>>>(G, sv,
                                         psiW3 + (size_t)i * 32768, psib3 + i * 256,
                                         phiW3 + (size_t)i * 32768, phib3 + i * 256,
                                         H2phi, x2c);
        k_epilogue<<<8192, 256, 0, stream>>>(x1, yl1, yl2, x2c,
                                             lnG + i * 64, lnB + i * 64,
                                             hbf, (i < 3) ? 1 : 0);
    }

    k_head_mfma<<<1024, 256, 0, stream>>>(hbf, q1bf, q1b, q2W, q2b, (float*)d_out);
}

// Round 8
// 578.085 us; speedup vs baseline: 1.2604x; 1.1019x over previous
//
#include <hip/hip_runtime.h>
#include <cstddef>
#include <cstdint>

// ---------------- problem constants ----------------
// b=2, s=256, WIDTH=64, RANK=4, CLEVEL=1 (c=2), MLEVEL=2 (L=3), NB=4
// HID1=64, HID2=128

// ---------------- workspace layout (float offsets) ----------------
static constexpr size_t OFF_X1     = 0;          // 8388608
static constexpr size_t OFF_YL1    = 8388608;    // 2097152
static constexpr size_t OFF_YL2    = 10485760;   // 524288
static constexpr size_t OFF_HBF    = 11010048;   // bf16 h: 8388608 bf16 = 4194304 slots
static constexpr size_t OFF_H2PSI  = 15204352;   // 4194304 (x2c overlays after k_gpart)
static constexpr size_t OFF_H2PHI  = 19398656;   // 4194304
static constexpr size_t OFF_CWTBF  = 23592960;   // 221184
static constexpr size_t OFF_Q1BF   = 23814144;   // 4096
static constexpr size_t OFF_GPART  = 23818240;   // 512*8192 = 4194304
static constexpr size_t OFF_SVP    = 28012544;   // 512*64 = 32768
static constexpr size_t OFF_G      = 28045312;   // 16384
static constexpr size_t OFF_SV     = 28061696;   // 128
static constexpr size_t OFF_C      = 28061824;   // 16384
static constexpr size_t OFF_D      = 28078208;   // 128
// end = 28078336 floats (~112 MB) <= proven-available 134.3 MB

typedef __attribute__((ext_vector_type(8)))  short bf16x8_t;   // 8 bf16 in 4 VGPRs
typedef __attribute__((ext_vector_type(16))) float f32x16_t;   // 32x32 MFMA acc

// ---------------- helpers ----------------
__device__ inline float wave_sum64(float v) {
    v += __shfl_xor(v, 1);
    v += __shfl_xor(v, 2);
    v += __shfl_xor(v, 4);
    v += __shfl_xor(v, 8);
    v += __shfl_xor(v, 16);
    v += __shfl_xor(v, 32);
    return v;
}

__device__ inline unsigned short f2bf(float f) {   // round-to-nearest-even
    uint32_t u = __float_as_uint(f);
    uint32_t r = u + 0x7FFFu + ((u >> 16) & 1u);
    return (unsigned short)(r >> 16);
}

// full-res flat pixel index of coarse pixel (b, n): n in [0,16384)
__device__ inline size_t fullpix(int b, int n) {
    return (size_t)(b * 65536 + (n >> 7) * 512 + ((n & 127) << 1));
}

struct Lerp { int i0, i1; float f; };
__device__ inline Lerp lcoord(int o, float r, float off, int Sin) {
    float s = fmaxf(fmaf((float)o, r, off), 0.f);
    Lerp L;
    L.i0 = (int)s;
    L.f  = s - (float)L.i0;
    L.i1 = min(L.i0 + 1, Sin - 1);
    return L;
}
__device__ inline float bilerp64(const float* __restrict__ base, int Sin,
                                 const Lerp& ly, const Lerp& lx, int lane) {
    float v00 = base[((size_t)(ly.i0 * Sin + lx.i0)) * 64 + lane];
    float v01 = base[((size_t)(ly.i0 * Sin + lx.i1)) * 64 + lane];
    float v10 = base[((size_t)(ly.i1 * Sin + lx.i0)) * 64 + lane];
    float v11 = base[((size_t)(ly.i1 * Sin + lx.i1)) * 64 + lane];
    float a = v00 + lx.f * (v01 - v00);
    float b = v10 + lx.f * (v11 - v10);
    return a + ly.f * (b - a);
}

// ---------------- weight transforms ----------------
// convW[i][l][oc][ic][3][3] f32 -> cwtbf[i*3+l][oc][tap*64+ic] bf16
__global__ __launch_bounds__(256) void k_transpose_convw_bf(const float* __restrict__ w,
                                                            unsigned short* __restrict__ wt) {
    int idx = blockIdx.x * 256 + threadIdx.x;     // 12*64*576 = 442368
    if (idx >= 442368) return;
    int k    = idx % 576;
    int rest = idx / 576;
    int oc   = rest & 63;
    int il   = rest >> 6;
    int tap  = k >> 6;
    int ic   = k & 63;
    wt[idx] = f2bf(w[((size_t)(il * 64 + oc) * 64 + ic) * 9 + tap]);
}
// q1W[64][128] f32 -> q1bf[j][k] bf16 (transposed)
__global__ __launch_bounds__(256) void k_transpose_q1bf(const float* __restrict__ w,
                                                        unsigned short* __restrict__ wt) {
    int idx = blockIdx.x * 256 + threadIdx.x;     // 8192
    if (idx >= 8192) return;
    int k = idx & 63;
    int j = idx >> 6;
    wt[j * 64 + k] = f2bf(w[k * 128 + j]);
}

// ---------------- lift: h = [a0,a1,x] @ pW + pb (writes bf16 NHWC) ----------------
__global__ __launch_bounds__(256) void k_lift(const float* __restrict__ x,
                                              const float* __restrict__ a,
                                              const float* __restrict__ pW,
                                              const float* __restrict__ pb,
                                              unsigned short* __restrict__ hbf) {
    int p = blockIdx.x * 256 + threadIdx.x;       // 131072
    float a0 = a[(size_t)p * 2 + 0];
    float a1 = a[(size_t)p * 2 + 1];
    float xv = x[p];
    float vals[64];
#pragma unroll
    for (int c = 0; c < 64; ++c)
        vals[c] = fmaf(a0, pW[c], fmaf(a1, pW[64 + c], fmaf(xv, pW[128 + c], pb[c])));
    unsigned short us[64];
#pragma unroll
    for (int c = 0; c < 64; ++c) us[c] = f2bf(vals[c]);
    unsigned short* bp = hbf + (size_t)p * 64;
#pragma unroll
    for (int c = 0; c < 64; c += 8)
        *(uint4*)(bp + c) = *(uint4*)(us + c);
}

// ---------------- MFMA conv 3x3 SAME (64->64), oc-split for 2 blocks/CU ----------------
// Each block: 16x16 px tile x 32 output channels. Grid 1344.
__global__ __launch_bounds__(256) void k_conv_mfma(
    const unsigned short* __restrict__ hbf,   // [2][256][256][64] bf16
    const unsigned short* __restrict__ wbf,   // [12][64][576] bf16
    const float* __restrict__ convb,          // [12][64]
    float* __restrict__ x1, float* __restrict__ yl1, float* __restrict__ yl2,
    int iter) {
    __shared__ unsigned short Ald[20736];     // 324 px * 64 ic  (41472 B)
    __shared__ unsigned short Bld[18432];     // 32 oc * 576 k   (36864 B)

    int bid = blockIdx.x;
    int lvl, q2_, Sl, st, tpr;
    if (bid < 1024)      { lvl = 0; q2_ = bid;        Sl = 256; st = 1; tpr = 16; }
    else if (bid < 1280) { lvl = 1; q2_ = bid - 1024; Sl = 128; st = 2; tpr = 8;  }
    else                 { lvl = 2; q2_ = bid - 1280; Sl = 64;  st = 4; tpr = 4;  }
    int tix = q2_ >> 1;
    int oc0 = (q2_ & 1) << 5;
    int tpb = tpr * tpr;
    int b = tix / tpb;
    int r = tix - b * tpb;
    int y0 = (r / tpr) * 16, x0 = (r % tpr) * 16;
    int t = threadIdx.x;

    // ---- stage A: 18x18 halo x 64 ic, zero-padded at image edges ----
    for (int c = t; c < 2592; c += 256) {       // 324 rows * 8 slots(16B)
        int lin = c >> 3, slot = c & 7;
        int ty = lin / 18, tx = lin - ty * 18;
        int oy = y0 + ty - 1, ox = x0 + tx - 1;
        uint4 val = make_uint4(0u, 0u, 0u, 0u);
        if ((unsigned)oy < (unsigned)Sl && (unsigned)ox < (unsigned)Sl) {
            const unsigned short* src =
                hbf + (((size_t)(b * 256 + oy * st) * 256 + ox * st) << 6) + (slot << 3);
            val = *(const uint4*)src;
        }
        int byte = (lin << 7) + (((slot ^ (lin & 7))) << 4);
        *(uint4*)((char*)Ald + byte) = val;
    }
    // ---- stage B: 32 oc rows of weights for this (iter,lvl,oc0) ----
    {
        const unsigned short* wsrc = wbf + (size_t)(iter * 3 + lvl) * 36864 + (size_t)oc0 * 576;
        int ocl = t >> 3, q = t & 7;
#pragma unroll
        for (int j = 0; j < 18; ++j) {
            int ke = q * 72 + j * 4;                    // bf16 elems
            uint2 v = *(const uint2*)(wsrc + ocl * 576 + ke);
            int byte = (ocl * 1152 + (ke << 1)) ^ ((ocl & 7) << 4);
            *(uint2*)((char*)Bld + byte) = v;
        }
    }
    __syncthreads();

    // ---- compute ----
    int w    = t >> 6;
    int lane = t & 63;
    int lo   = lane & 31;
    int hi   = lane >> 5;
    f32x16_t acc00 = {}, acc10 = {};

    int yA0 = 4 * w + (lo >> 4);
    int xA  = lo & 15;
#pragma unroll 3
    for (int tap = 0; tap < 9; ++tap) {
        int dy = tap / 3, dx = tap - dy * 3;
        int lin0 = (yA0 + dy) * 18 + (xA + dx);
        int lin1 = lin0 + 36;
#pragma unroll
        for (int kq = 0; kq < 4; ++kq) {
            int icb = (kq << 5) + (hi << 4);
            int a0b = ((lin0 << 7) + icb) ^ ((lin0 & 7) << 4);
            int a1b = ((lin1 << 7) + icb) ^ ((lin1 & 7) << 4);
            bf16x8_t va0 = *(bf16x8_t*)((char*)Ald + a0b);
            bf16x8_t va1 = *(bf16x8_t*)((char*)Ald + a1b);
            int kk  = tap * 128 + icb;
            int b0b = (lo * 1152 + kk) ^ ((lo & 7) << 4);
            bf16x8_t vb0 = *(bf16x8_t*)((char*)Bld + b0b);
            acc00 = __builtin_amdgcn_mfma_f32_32x32x16_bf16(va0, vb0, acc00, 0, 0, 0);
            acc10 = __builtin_amdgcn_mfma_f32_32x32x16_bf16(va1, vb0, acc10, 0, 0, 0);
        }
    }

    // ---- store ----
    float* out = (lvl == 0) ? x1 : (lvl == 1 ? yl1 : yl2);
    float bias0 = convb[(iter * 3 + lvl) * 64 + oc0 + lo];
#pragma unroll
    for (int reg = 0; reg < 16; ++reg) {
        int row = (reg & 3) + 8 * (reg >> 2) + 4 * hi;
        int yt  = 4 * w + (row >> 4);
        int xt  = row & 15;
        size_t pix0 = ((size_t)(b * Sl + y0 + yt) * Sl + (x0 + xt)) << 6;
        out[pix0 + oc0 + lo] = acc00[reg] + bias0;
        size_t pix1 = ((size_t)(b * Sl + y0 + yt + 2) * Sl + (x0 + xt)) << 6;
        out[pix1 + oc0 + lo] = acc10[reg] + bias0;
    }
}

// ---------------- mlp12: H2 = relu(relu(a@W1+b1)@W2+b2), 4 threads/px ----------------
__global__ __launch_bounds__(256) void k_mlp12(
    const float* __restrict__ a, const float* __restrict__ x,
    const float* __restrict__ W1a, const float* __restrict__ b1a,
    const float* __restrict__ W2a, const float* __restrict__ b2a,
    const float* __restrict__ W1b, const float* __restrict__ b1b,
    const float* __restrict__ W2b, const float* __restrict__ b2b,
    float* __restrict__ H2a, float* __restrict__ H2b) {
    int blk = blockIdx.x;                          // 1024
    int m = blk >> 9;
    int t = threadIdx.x;
    int pxl = ((blk & 511) << 6) | (t & 63);       // 0..32767
    int j0 = __builtin_amdgcn_readfirstlane((t >> 6) << 5);  // 0/32/64/96
    const float* W1 = m ? W1b : W1a;
    const float* b1 = m ? b1b : b1a;
    const float* W2 = m ? W2b : W2a;
    const float* b2 = m ? b2b : b2a;
    float* H2 = m ? H2b : H2a;
    int b = pxl >> 14, n = pxl & 16383;
    size_t apix = fullpix(b, n);
    float a0 = a[apix * 2], a1 = a[apix * 2 + 1], xv = x[apix];

    float acc[32];
#pragma unroll
    for (int j = 0; j < 32; ++j) acc[j] = b2[j0 + j];
#pragma unroll 1
    for (int k = 0; k < 64; ++k) {
        float h1 = fmaxf(fmaf(a0, W1[k], fmaf(a1, W1[64 + k], fmaf(xv, W1[128 + k], b1[k]))), 0.f);
        const float* wr = W2 + k * 128 + j0;
#pragma unroll
        for (int j = 0; j < 32; ++j) acc[j] = fmaf(h1, wr[j], acc[j]);
    }
    float* op = H2 + (size_t)pxl * 128 + j0;
#pragma unroll
    for (int j = 0; j < 32; j += 4)
        *(float4*)(op + j) = make_float4(fmaxf(acc[j], 0.f), fmaxf(acc[j + 1], 0.f),
                                         fmaxf(acc[j + 2], 0.f), fmaxf(acc[j + 3], 0.f));
}

// ---------------- split-K stage 1: Gpart[blk] = v^T H2psi over 64 px; svpart ----------------
__global__ __launch_bounds__(256) void k_gpart(const unsigned short* __restrict__ hbf,
                                               const float* __restrict__ H2psi,
                                               float* __restrict__ Gpart,
                                               float* __restrict__ svpart) {
    __shared__ float vt[4096];       // [64 px][64 w]
    __shared__ float h2t[8192];      // [64 px][128 j]
    int blk = blockIdx.x;            // 512
    int b = blk >> 8;
    int n0 = (blk & 255) << 6;
    int t = threadIdx.x;
    int pxq = t >> 2, qq = t & 3;
    int sw = (pxq & 7) << 4;
    {
        const unsigned short* src = hbf + fullpix(b, n0 + pxq) * 64 + qq * 16;
        uint4 u0 = *(const uint4*)src;
        uint4 u1 = *(const uint4*)(src + 8);
        unsigned uv[8] = {u0.x, u0.y, u0.z, u0.w, u1.x, u1.y, u1.z, u1.w};
        float f[16];
#pragma unroll
        for (int i = 0; i < 8; ++i) {
            f[2 * i]     = __uint_as_float((uv[i] & 0xFFFFu) << 16);
            f[2 * i + 1] = __uint_as_float(uv[i] & 0xFFFF0000u);
        }
#pragma unroll
        for (int j = 0; j < 4; ++j) {
            int byte = (pxq * 256 + qq * 64 + j * 16) ^ sw;
            *(float4*)((char*)vt + byte) = make_float4(f[4 * j], f[4 * j + 1],
                                                       f[4 * j + 2], f[4 * j + 3]);
        }
        const float* hsrc = &H2psi[((size_t)(b * 16384 + n0 + pxq)) * 128 + qq * 32];
#pragma unroll
        for (int rr = 0; rr < 8; ++rr) {
            int byte = (pxq * 512 + qq * 128 + rr * 16) ^ sw;
            *(float4*)((char*)h2t + byte) = *(const float4*)(hsrc + rr * 4);
        }
    }
    __syncthreads();

    int wt_ = (t >> 5) << 3;         // 0..56
    int kt  = (t & 31) << 2;         // 0..124
    float acc[8][4];
#pragma unroll
    for (int i = 0; i < 8; ++i)
#pragma unroll
        for (int j = 0; j < 4; ++j) acc[i][j] = 0.f;

#pragma unroll 4
    for (int nn = 0; nn < 64; ++nn) {
        int nsw = (nn & 7) << 4;
        float4 hv = *(float4*)((char*)h2t + ((nn * 512 + kt * 4) ^ nsw));
        float4 v0 = *(float4*)((char*)vt + ((nn * 256 + wt_ * 4) ^ nsw));
        float4 v1 = *(float4*)((char*)vt + ((nn * 256 + wt_ * 4 + 16) ^ nsw));
        float vv[8] = {v0.x, v0.y, v0.z, v0.w, v1.x, v1.y, v1.z, v1.w};
        float hh[4] = {hv.x, hv.y, hv.z, hv.w};
#pragma unroll
        for (int i = 0; i < 8; ++i)
#pragma unroll
            for (int j = 0; j < 4; ++j) acc[i][j] = fmaf(vv[i], hh[j], acc[i][j]);
    }

    float* gp = Gpart + (size_t)blk * 8192;
#pragma unroll
    for (int i = 0; i < 8; ++i)
        *(float4*)&gp[(wt_ + i) * 128 + kt] =
            make_float4(acc[i][0], acc[i][1], acc[i][2], acc[i][3]);

    if (t < 64) {
        float s = 0.f;
#pragma unroll 8
        for (int p = 0; p < 64; ++p)
            s += *(float*)((char*)vt + ((p * 256 + t * 4) ^ ((p & 7) << 4)));
        svpart[blk * 64 + t] = s;
    }
}

// ---------------- reduce: G = sum Gpart; sv = sum svpart (grid 258) ----------------
__global__ __launch_bounds__(256) void k_gred(const float* __restrict__ Gpart,
                                              const float* __restrict__ svpart,
                                              float* __restrict__ G,
                                              float* __restrict__ sv) {
    __shared__ float red[4][64];
    int blk = blockIdx.x;
    int t = threadIdx.x;
    if (blk < 256) {
        int b  = blk >> 7;
        int es = (blk & 127) << 6;
        int e  = es + (t & 63);
        int cg = t >> 6;
        float s = 0.f;
        const float* gp = Gpart + ((size_t)(b * 256 + cg * 64)) * 8192 + e;
#pragma unroll 8
        for (int c = 0; c < 64; ++c) s += gp[(size_t)c * 8192];
        red[cg][t & 63] = s;
        __syncthreads();
        if (t < 64)
            G[b * 8192 + es + t] = red[0][t] + red[1][t] + red[2][t] + red[3][t];
    } else {
        int b = blk - 256;
        int w = t & 63, cg = t >> 6;
        float s = 0.f;
        const float* sp = svpart + ((size_t)(b * 256 + cg * 64)) * 64 + w;
#pragma unroll 8
        for (int c = 0; c < 64; ++c) s += sp[c * 64];
        red[cg][w] = s;
        __syncthreads();
        if (t < 64) sv[b * 64 + t] = red[0][t] + red[1][t] + red[2][t] + red[3][t];
    }
}

// ---------------- yc: ybar -> C[b][w][k], D[b][w] (grid 32) ----------------
__global__ __launch_bounds__(256) void k_yc(const float* __restrict__ G,
                                            const float* __restrict__ sv,
                                            const float* __restrict__ W3psi,
                                            const float* __restrict__ b3psi,
                                            const float* __restrict__ W3phi,
                                            const float* __restrict__ b3phi,
                                            float* __restrict__ C,
                                            float* __restrict__ D) {
    __shared__ float ybar[256];
    int bq = blockIdx.x;             // 32
    int b = bq >> 4, q = bq & 15;
    int t = threadIdx.x;
    {
        int o = t, w = o >> 2;
        const float* gp = &G[(size_t)(b * 64 + w) * 128];
        float s0 = 0.f, s1 = 0.f, s2 = 0.f, s3 = 0.f;
#pragma unroll 4
        for (int k = 0; k < 128; k += 4) {
            s0 = fmaf(W3psi[(k + 0) * 256 + o], gp[k + 0], s0);
            s1 = fmaf(W3psi[(k + 1) * 256 + o], gp[k + 1], s1);
            s2 = fmaf(W3psi[(k + 2) * 256 + o], gp[k + 2], s2);
            s3 = fmaf(W3psi[(k + 3) * 256 + o], gp[k + 3], s3);
        }
        float s = b3psi[o] * sv[b * 64 + w] + ((s0 + s1) + (s2 + s3));
        ybar[o] = s * (1.f / 16384.f);
    }
    __syncthreads();
#pragma unroll
    for (int rep = 0; rep < 2; ++rep) {
        int e = q * 512 + rep * 256 + t;   // this block's slice of 8192
        int w = e >> 7, k = e & 127;
        const float* wp = &W3phi[k * 256 + w * 4];
        C[b * 8192 + e] = fmaf(wp[0], ybar[w * 4],
                          fmaf(wp[1], ybar[w * 4 + 1],
                          fmaf(wp[2], ybar[w * 4 + 2], wp[3] * ybar[w * 4 + 3])));
    }
    if (q == 0 && t < 64) {
        int w = t;
        D[b * 64 + w] = b3phi[w * 4] * ybar[w * 4] + b3phi[w * 4 + 1] * ybar[w * 4 + 1]
                      + b3phi[w * 4 + 2] * ybar[w * 4 + 2] + b3phi[w * 4 + 3] * ybar[w * 4 + 3];
    }
}

// ---------------- x2c: x2c[px][w] = H2phi[px][:].C[b][w][:] + D[b][w] (grid 1024) ----------------
__global__ __launch_bounds__(256) void k_x2c(const float* __restrict__ H2phi,
                                             const float* __restrict__ C,
                                             const float* __restrict__ D,
                                             float* __restrict__ x2c) {
    __shared__ float cl[8192];       // C[b]: [64 w][128 k]  (32 KB)
    __shared__ float h2l[4096];      // [32 px][128 k], XOR-swizzled (16 KB)
    __shared__ float Dl[64];
    int blk = blockIdx.x;            // 1024: 512 per b
    int b = blk >> 9;
    int px0 = (blk & 511) << 5;      // 32 px per block
    int t = threadIdx.x;

    const float* cp = C + b * 8192;
#pragma unroll
    for (int r = 0; r < 8; ++r) {
        int f = r * 1024 + t * 4;
        *(float4*)&cl[f] = *(const float4*)&cp[f];
    }
    if (t < 64) Dl[t] = D[b * 64 + t];
    {   // stage H2phi tile: 4096 floats, coalesced float4 loads, swizzled stores
        const float* hsrc = H2phi + ((size_t)(b * 16384 + px0)) * 128;
#pragma unroll
        for (int r = 0; r < 4; ++r) {
            int f = r * 1024 + t * 4;              // float index
            int px = f >> 7;
            int byte = (f * 4) ^ ((px & 7) << 4) ^ (((px >> 3) & 1) << 6);
            *(float4*)((char*)h2l + byte) = *(const float4*)&hsrc[f];
        }
    }
    __syncthreads();

    int px = t & 31;
    int w0 = (t >> 5) << 3;          // 0..56: 8 w per thread
    int psw = ((px & 7) << 4) ^ (((px >> 3) & 1) << 6);
    float acc[8];
#pragma unroll
    for (int j = 0; j < 8; ++j) acc[j] = 0.f;

#pragma unroll 4
    for (int kq = 0; kq < 32; ++kq) {
        float4 hq = *(float4*)((char*)h2l + ((px * 512 + kq * 16) ^ psw));
#pragma unroll
        for (int j = 0; j < 8; ++j) {
            float4 cq = *(float4*)&cl[(w0 + j) * 128 + kq * 4];
            acc[j] = fmaf(hq.x, cq.x, acc[j]);
            acc[j] = fmaf(hq.y, cq.y, acc[j]);
            acc[j] = fmaf(hq.z, cq.z, acc[j]);
            acc[j] = fmaf(hq.w, cq.w, acc[j]);
        }
    }
    float* op = &x2c[((size_t)(b * 16384 + px0 + px)) * 64 + w0];
    *(float4*)(op)     = make_float4(acc[0] + Dl[w0],     acc[1] + Dl[w0 + 1],
                                     acc[2] + Dl[w0 + 2], acc[3] + Dl[w0 + 3]);
    *(float4*)(op + 4) = make_float4(acc[4] + Dl[w0 + 4], acc[5] + Dl[w0 + 5],
                                     acc[6] + Dl[w0 + 6], acc[7] + Dl[w0 + 7]);
}

// ---------------- epilogue: h = LN(x1 + up(yl1) + up(yl2) + up(x2c)); writes bf16 ----------------
__global__ __launch_bounds__(256) void k_epilogue(const float* __restrict__ x1,
                                                  const float* __restrict__ yl1,
                                                  const float* __restrict__ yl2,
                                                  const float* __restrict__ x2c,
                                                  const float* __restrict__ lnG,
                                                  const float* __restrict__ lnB,
                                                  unsigned short* __restrict__ hbf,
                                                  int do_relu) {
    int t    = threadIdx.x;
    int blk  = blockIdx.x;                 // 8192 = 2 * 256 * 16
    int b    = blk >> 12;
    int rest = blk & 4095;
    int y    = rest >> 4;
    int x0   = (rest & 15) << 4;
    int wv = t >> 6, lane = t & 63;

    float g = lnG[lane], be = lnB[lane];
    const float* Y1 = yl1 + (size_t)b * 16384 * 64;
    const float* Y2 = yl2 + (size_t)b * 4096 * 64;
    const float* XC = x2c + (size_t)b * 16384 * 64;

    for (int pp = 0; pp < 4; ++pp) {
        int xx = x0 + wv * 4 + pp;
        size_t pix = (size_t)((b * 256 + y) * 256 + xx);
        float v = x1[pix * 64 + lane];
        {
            Lerp ly = lcoord(y, 0.5f, -0.25f, 128);
            Lerp lx = lcoord(xx, 0.5f, -0.25f, 128);
            v += bilerp64(Y1, 128, ly, lx, lane);
        }
        {
            Lerp ly = lcoord(y, 0.25f, -0.375f, 64);
            Lerp lx = lcoord(xx, 0.25f, -0.375f, 64);
            v += bilerp64(Y2, 64, ly, lx, lane);
        }
        {
            Lerp ly = lcoord(y, 0.5f, -0.25f, 128);
            Lerp lx = lcoord(xx, 0.5f, -0.25f, 128);
            v += bilerp64(XC, 128, ly, lx, lane);
        }
        float mu  = wave_sum64(v) * (1.f / 64.f);
        float d   = v - mu;
        float var = wave_sum64(d * d) * (1.f / 64.f);
        float ov  = fmaf(d * rsqrtf(var + 1e-5f), g, be);
        if (do_relu) ov = fmaxf(ov, 0.f);
        hbf[pix * 64 + lane] = f2bf(ov);
    }
}

// ---------------- head (MFMA): out = relu(hbf@q1W+q1b) . q2 + q2b ----------------
__global__ __launch_bounds__(256) void k_head_mfma(
    const unsigned short* __restrict__ hbf,   // [131072][64] bf16
    const unsigned short* __restrict__ q1bf,  // [128 j][64 k] bf16
    const float* __restrict__ q1b,            // [128]
    const float* __restrict__ q2,             // [128]
    const float* __restrict__ q2b,            // [1]
    float* __restrict__ out) {
    __shared__ unsigned short Q[8192];        // [j][k] swizzled
    int t = threadIdx.x;
    for (int c = t; c < 1024; c += 256) {
        int j = c >> 3, slot = c & 7;
        uint4 v = *(const uint4*)(q1bf + j * 64 + slot * 8);
        int byte = (j * 128 + slot * 16) ^ ((j & 7) << 4);
        *(uint4*)((char*)Q + byte) = v;
    }
    __syncthreads();

    int w = t >> 6, lane = t & 63;
    int lo = lane & 31, hi = lane >> 5;
    int px0 = blockIdx.x * 128 + w * 32;      // grid 1024

    bf16x8_t av[4];
    const unsigned short* hp = hbf + (size_t)(px0 + lo) * 64 + hi * 8;
#pragma unroll
    for (int ks = 0; ks < 4; ++ks)
        av[ks] = *(const bf16x8_t*)(hp + ks * 16);

    float res[16];
#pragma unroll
    for (int r = 0; r < 16; ++r) res[r] = 0.f;

#pragma unroll
    for (int jb = 0; jb < 4; ++jb) {
        f32x16_t acc = {};
        int j = jb * 32 + lo;
#pragma unroll
        for (int ks = 0; ks < 4; ++ks) {
            int byte = (j * 128 + ks * 32 + hi * 16) ^ ((j & 7) << 4);
            bf16x8_t bv = *(bf16x8_t*)((char*)Q + byte);
            acc = __builtin_amdgcn_mfma_f32_32x32x16_bf16(av[ks], bv, acc, 0, 0, 0);
        }
        float b1 = q1b[j];
        float w2 = q2[j];
#pragma unroll
        for (int r = 0; r < 16; ++r)
            res[r] = fmaf(fmaxf(acc[r] + b1, 0.f), w2, res[r]);
    }
#pragma unroll
    for (int r = 0; r < 16; ++r) {
        float v = res[r];
        v += __shfl_xor(v, 1);
        v += __shfl_xor(v, 2);
        v += __shfl_xor(v, 4);
        v += __shfl_xor(v, 8);
        v += __shfl_xor(v, 16);
        res[r] = v;
    }
    if (lo == 0) {
        float qb = q2b[0];
#pragma unroll
        for (int r = 0; r < 16; ++r) {
            int row = (r & 3) + 8 * (r >> 2) + 4 * hi;
            out[px0 + row] = res[r] + qb;
        }
    }
}

// ---------------- launch ----------------
extern "C" void kernel_launch(void* const* d_in, const int* in_sizes, int n_in,
                              void* d_out, int out_size, void* d_ws, size_t ws_size,
                              hipStream_t stream) {
    const float* x     = (const float*)d_in[0];
    const float* a     = (const float*)d_in[1];
    const float* pW    = (const float*)d_in[2];
    const float* pb    = (const float*)d_in[3];
    const float* q1W   = (const float*)d_in[4];
    const float* q1b   = (const float*)d_in[5];
    const float* q2W   = (const float*)d_in[6];
    const float* q2b   = (const float*)d_in[7];
    const float* phiW1 = (const float*)d_in[8];
    const float* phib1 = (const float*)d_in[9];
    const float* phiW2 = (const float*)d_in[10];
    const float* phib2 = (const float*)d_in[11];
    const float* phiW3 = (const float*)d_in[12];
    const float* phib3 = (const float*)d_in[13];
    const float* psiW1 = (const float*)d_in[14];
    const float* psib1 = (const float*)d_in[15];
    const float* psiW2 = (const float*)d_in[16];
    const float* psib2 = (const float*)d_in[17];
    const float* psiW3 = (const float*)d_in[18];
    const float* psib3 = (const float*)d_in[19];
    const float* lnG   = (const float*)d_in[20];
    const float* lnB   = (const float*)d_in[21];
    const float* convW = (const float*)d_in[22];
    const float* convb = (const float*)d_in[23];

    float* ws    = (float*)d_ws;
    float* x1    = ws + OFF_X1;
    float* yl1   = ws + OFF_YL1;
    float* yl2   = ws + OFF_YL2;
    unsigned short* hbf = (unsigned short*)(ws + OFF_HBF);
    float* H2psi = ws + OFF_H2PSI;
    float* x2c   = ws + OFF_H2PSI;            // overlay: H2psi dead after k_gpart
    float* H2phi = ws + OFF_H2PHI;
    unsigned short* cwtbf = (unsigned short*)(ws + OFF_CWTBF);
    unsigned short* q1bf  = (unsigned short*)(ws + OFF_Q1BF);
    float* Gpart = ws + OFF_GPART;
    float* svpart= ws + OFF_SVP;
    float* G     = ws + OFF_G;
    float* sv    = ws + OFF_SV;
    float* C     = ws + OFF_C;
    float* D     = ws + OFF_D;

    k_transpose_convw_bf<<<1728, 256, 0, stream>>>(convW, cwtbf);
    k_transpose_q1bf<<<32, 256, 0, stream>>>(q1W, q1bf);

    k_lift<<<512, 256, 0, stream>>>(x, a, pW, pb, hbf);

    for (int i = 0; i < 4; ++i) {
        k_conv_mfma<<<1344, 256, 0, stream>>>(hbf, cwtbf, convb, x1, yl1, yl2, i);
        k_mlp12<<<1024, 256, 0, stream>>>(a, x,
                                          psiW1 + i * 192, psib1 + i * 64,
                                          psiW2 + i * 8192, psib2 + i * 128,
                                          phiW1 + i * 192, phib1 + i * 64,
                                          phiW2 + i * 8192, phib2 + i * 128,
                                          H2psi, H2phi);
        k_gpart<<<512, 256, 0, stream>>>(hbf, H2psi, Gpart, svpart);
        k_gred<<<258, 256, 0, stream>>>(Gpart, svpart, G, sv);
        k_yc<<<32, 256, 0, stream>>>(G, sv,
                                     psiW3 + (size_t)i * 32768, psib3 + i * 256,
                                     phiW3 + (size_t)i * 32768, phib3 + i * 256,
                                     C, D);
        k_x2c<<<1024, 256, 0, stream>>>(H2phi, C, D, x2c);
        k_epilogue<<<8192, 256, 0, stream>>>(x1, yl1, yl2, x2c,
                                             lnG + i * 64, lnB + i * 64,
                                             hbf, (i < 3) ? 1 : 0);
    }

    k_head_mfma<<<1024, 256, 0, stream>>>(hbf, q1bf, q1b, q2W, q2b, (float*)d_out);
}

// Round 9
// 559.028 us; speedup vs baseline: 1.3034x; 1.0341x over previous
//
#include <hip/hip_runtime.h>
#include <cstddef>
#include <cstdint>

// ---------------- problem constants ----------------
// b=2, s=256, WIDTH=64, RANK=4, CLEVEL=1 (c=2), MLEVEL=2 (L=3), NB=4
// HID1=64, HID2=128

// ---------------- workspace layout (float offsets) ----------------
static constexpr size_t OFF_X1     = 0;          // 8388608
static constexpr size_t OFF_YL1    = 8388608;    // 2097152
static constexpr size_t OFF_YL2    = 10485760;   // 524288
static constexpr size_t OFF_HBF    = 11010048;   // bf16 h: 8388608 bf16 = 4194304 slots
static constexpr size_t OFF_H2PSI  = 15204352;   // 4194304 (x2c overlays after k_gpart)
static constexpr size_t OFF_H2PHI  = 19398656;   // 4194304
static constexpr size_t OFF_CWTBF  = 23592960;   // 221184
static constexpr size_t OFF_Q1BF   = 23814144;   // 4096
static constexpr size_t OFF_GPART  = 23818240;   // 512*8192 = 4194304
static constexpr size_t OFF_SVP    = 28012544;   // 512*64 = 32768
static constexpr size_t OFF_G      = 28045312;   // 16384
static constexpr size_t OFF_SV     = 28061696;   // 128
static constexpr size_t OFF_C      = 28061824;   // 16384
static constexpr size_t OFF_D      = 28078208;   // 128
// end = 28078336 floats (~112 MB) <= proven-available 134.3 MB

typedef __attribute__((ext_vector_type(8)))  short bf16x8_t;   // 8 bf16 in 4 VGPRs
typedef __attribute__((ext_vector_type(16))) float f32x16_t;   // 32x32 MFMA acc

// ---------------- helpers ----------------
__device__ inline float wave_sum64(float v) {
    v += __shfl_xor(v, 1);
    v += __shfl_xor(v, 2);
    v += __shfl_xor(v, 4);
    v += __shfl_xor(v, 8);
    v += __shfl_xor(v, 16);
    v += __shfl_xor(v, 32);
    return v;
}

__device__ inline unsigned short f2bf(float f) {   // round-to-nearest-even
    uint32_t u = __float_as_uint(f);
    uint32_t r = u + 0x7FFFu + ((u >> 16) & 1u);
    return (unsigned short)(r >> 16);
}

// full-res flat pixel index of coarse pixel (b, n): n in [0,16384)
__device__ inline size_t fullpix(int b, int n) {
    return (size_t)(b * 65536 + (n >> 7) * 512 + ((n & 127) << 1));
}

struct Lerp { int i0, i1; float f; };
__device__ inline Lerp lcoord(int o, float r, float off, int Sin) {
    float s = fmaxf(fmaf((float)o, r, off), 0.f);
    Lerp L;
    L.i0 = (int)s;
    L.f  = s - (float)L.i0;
    L.i1 = min(L.i0 + 1, Sin - 1);
    return L;
}

// ---------------- weight transforms ----------------
// convW[i][l][oc][ic][3][3] f32 -> cwtbf[i*3+l][oc][tap*64+ic] bf16
__global__ __launch_bounds__(256) void k_transpose_convw_bf(const float* __restrict__ w,
                                                            unsigned short* __restrict__ wt) {
    int idx = blockIdx.x * 256 + threadIdx.x;     // 12*64*576 = 442368
    if (idx >= 442368) return;
    int k    = idx % 576;
    int rest = idx / 576;
    int oc   = rest & 63;
    int il   = rest >> 6;
    int tap  = k >> 6;
    int ic   = k & 63;
    wt[idx] = f2bf(w[((size_t)(il * 64 + oc) * 64 + ic) * 9 + tap]);
}
// q1W[64][128] f32 -> q1bf[j][k] bf16 (transposed)
__global__ __launch_bounds__(256) void k_transpose_q1bf(const float* __restrict__ w,
                                                        unsigned short* __restrict__ wt) {
    int idx = blockIdx.x * 256 + threadIdx.x;     // 8192
    if (idx >= 8192) return;
    int k = idx & 63;
    int j = idx >> 6;
    wt[j * 64 + k] = f2bf(w[k * 128 + j]);
}

// ---------------- lift: h = [a0,a1,x] @ pW + pb (writes bf16 NHWC) ----------------
__global__ __launch_bounds__(256) void k_lift(const float* __restrict__ x,
                                              const float* __restrict__ a,
                                              const float* __restrict__ pW,
                                              const float* __restrict__ pb,
                                              unsigned short* __restrict__ hbf) {
    int p = blockIdx.x * 256 + threadIdx.x;       // 131072
    float a0 = a[(size_t)p * 2 + 0];
    float a1 = a[(size_t)p * 2 + 1];
    float xv = x[p];
    float vals[64];
#pragma unroll
    for (int c = 0; c < 64; ++c)
        vals[c] = fmaf(a0, pW[c], fmaf(a1, pW[64 + c], fmaf(xv, pW[128 + c], pb[c])));
    unsigned short us[64];
#pragma unroll
    for (int c = 0; c < 64; ++c) us[c] = f2bf(vals[c]);
    unsigned short* bp = hbf + (size_t)p * 64;
#pragma unroll
    for (int c = 0; c < 64; c += 8)
        *(uint4*)(bp + c) = *(uint4*)(us + c);
}

// ---------------- MFMA conv 3x3 SAME (64->64), oc-split for 2 blocks/CU ----------------
// Each block: 16x16 px tile x 32 output channels. Grid 1344.
__global__ __launch_bounds__(256) void k_conv_mfma(
    const unsigned short* __restrict__ hbf,   // [2][256][256][64] bf16
    const unsigned short* __restrict__ wbf,   // [12][64][576] bf16
    const float* __restrict__ convb,          // [12][64]
    float* __restrict__ x1, float* __restrict__ yl1, float* __restrict__ yl2,
    int iter) {
    __shared__ unsigned short Ald[20736];     // 324 px * 64 ic  (41472 B)
    __shared__ unsigned short Bld[18432];     // 32 oc * 576 k   (36864 B)

    int bid = blockIdx.x;
    int lvl, q2_, Sl, st, tpr;
    if (bid < 1024)      { lvl = 0; q2_ = bid;        Sl = 256; st = 1; tpr = 16; }
    else if (bid < 1280) { lvl = 1; q2_ = bid - 1024; Sl = 128; st = 2; tpr = 8;  }
    else                 { lvl = 2; q2_ = bid - 1280; Sl = 64;  st = 4; tpr = 4;  }
    int tix = q2_ >> 1;
    int oc0 = (q2_ & 1) << 5;
    int tpb = tpr * tpr;
    int b = tix / tpb;
    int r = tix - b * tpb;
    int y0 = (r / tpr) * 16, x0 = (r % tpr) * 16;
    int t = threadIdx.x;

    // ---- stage A: 18x18 halo x 64 ic, zero-padded at image edges ----
    for (int c = t; c < 2592; c += 256) {       // 324 rows * 8 slots(16B)
        int lin = c >> 3, slot = c & 7;
        int ty = lin / 18, tx = lin - ty * 18;
        int oy = y0 + ty - 1, ox = x0 + tx - 1;
        uint4 val = make_uint4(0u, 0u, 0u, 0u);
        if ((unsigned)oy < (unsigned)Sl && (unsigned)ox < (unsigned)Sl) {
            const unsigned short* src =
                hbf + (((size_t)(b * 256 + oy * st) * 256 + ox * st) << 6) + (slot << 3);
            val = *(const uint4*)src;
        }
        int byte = (lin << 7) + (((slot ^ (lin & 7))) << 4);
        *(uint4*)((char*)Ald + byte) = val;
    }
    // ---- stage B: 32 oc rows of weights for this (iter,lvl,oc0) ----
    {
        const unsigned short* wsrc = wbf + (size_t)(iter * 3 + lvl) * 36864 + (size_t)oc0 * 576;
        int ocl = t >> 3, q = t & 7;
#pragma unroll
        for (int j = 0; j < 18; ++j) {
            int ke = q * 72 + j * 4;                    // bf16 elems
            uint2 v = *(const uint2*)(wsrc + ocl * 576 + ke);
            int byte = (ocl * 1152 + (ke << 1)) ^ ((ocl & 7) << 4);
            *(uint2*)((char*)Bld + byte) = v;
        }
    }
    __syncthreads();

    // ---- compute ----
    int w    = t >> 6;
    int lane = t & 63;
    int lo   = lane & 31;
    int hi   = lane >> 5;
    f32x16_t acc00 = {}, acc10 = {};

    int yA0 = 4 * w + (lo >> 4);
    int xA  = lo & 15;
#pragma unroll 3
    for (int tap = 0; tap < 9; ++tap) {
        int dy = tap / 3, dx = tap - dy * 3;
        int lin0 = (yA0 + dy) * 18 + (xA + dx);
        int lin1 = lin0 + 36;
#pragma unroll
        for (int kq = 0; kq < 4; ++kq) {
            int icb = (kq << 5) + (hi << 4);
            int a0b = ((lin0 << 7) + icb) ^ ((lin0 & 7) << 4);
            int a1b = ((lin1 << 7) + icb) ^ ((lin1 & 7) << 4);
            bf16x8_t va0 = *(bf16x8_t*)((char*)Ald + a0b);
            bf16x8_t va1 = *(bf16x8_t*)((char*)Ald + a1b);
            int kk  = tap * 128 + icb;
            int b0b = (lo * 1152 + kk) ^ ((lo & 7) << 4);
            bf16x8_t vb0 = *(bf16x8_t*)((char*)Bld + b0b);
            acc00 = __builtin_amdgcn_mfma_f32_32x32x16_bf16(va0, vb0, acc00, 0, 0, 0);
            acc10 = __builtin_amdgcn_mfma_f32_32x32x16_bf16(va1, vb0, acc10, 0, 0, 0);
        }
    }

    // ---- store ----
    float* out = (lvl == 0) ? x1 : (lvl == 1 ? yl1 : yl2);
    float bias0 = convb[(iter * 3 + lvl) * 64 + oc0 + lo];
#pragma unroll
    for (int reg = 0; reg < 16; ++reg) {
        int row = (reg & 3) + 8 * (reg >> 2) + 4 * hi;
        int yt  = 4 * w + (row >> 4);
        int xt  = row & 15;
        size_t pix0 = ((size_t)(b * Sl + y0 + yt) * Sl + (x0 + xt)) << 6;
        out[pix0 + oc0 + lo] = acc00[reg] + bias0;
        size_t pix1 = ((size_t)(b * Sl + y0 + yt + 2) * Sl + (x0 + xt)) << 6;
        out[pix1 + oc0 + lo] = acc10[reg] + bias0;
    }
}

// ---------------- mlp12: H2 = relu(relu(a@W1+b1)@W2+b2), 4 threads/px ----------------
__global__ __launch_bounds__(256) void k_mlp12(
    const float* __restrict__ a, const float* __restrict__ x,
    const float* __restrict__ W1a, const float* __restrict__ b1a,
    const float* __restrict__ W2a, const float* __restrict__ b2a,
    const float* __restrict__ W1b, const float* __restrict__ b1b,
    const float* __restrict__ W2b, const float* __restrict__ b2b,
    float* __restrict__ H2a, float* __restrict__ H2b) {
    int blk = blockIdx.x;                          // 1024
    int m = blk >> 9;
    int t = threadIdx.x;
    int pxl = ((blk & 511) << 6) | (t & 63);       // 0..32767
    int j0 = __builtin_amdgcn_readfirstlane((t >> 6) << 5);  // 0/32/64/96
    const float* W1 = m ? W1b : W1a;
    const float* b1 = m ? b1b : b1a;
    const float* W2 = m ? W2b : W2a;
    const float* b2 = m ? b2b : b2a;
    float* H2 = m ? H2b : H2a;
    int b = pxl >> 14, n = pxl & 16383;
    size_t apix = fullpix(b, n);
    float a0 = a[apix * 2], a1 = a[apix * 2 + 1], xv = x[apix];

    float acc[32];
#pragma unroll
    for (int j = 0; j < 32; ++j) acc[j] = b2[j0 + j];
#pragma unroll 2
    for (int k = 0; k < 64; ++k) {
        float h1 = fmaxf(fmaf(a0, W1[k], fmaf(a1, W1[64 + k], fmaf(xv, W1[128 + k], b1[k]))), 0.f);
        const float* wr = W2 + k * 128 + j0;
#pragma unroll
        for (int j = 0; j < 32; ++j) acc[j] = fmaf(h1, wr[j], acc[j]);
    }
    float* op = H2 + (size_t)pxl * 128 + j0;
#pragma unroll
    for (int j = 0; j < 32; j += 4)
        *(float4*)(op + j) = make_float4(fmaxf(acc[j], 0.f), fmaxf(acc[j + 1], 0.f),
                                         fmaxf(acc[j + 2], 0.f), fmaxf(acc[j + 3], 0.f));
}

// ---------------- split-K stage 1: Gpart[blk] = v^T H2psi over 64 px; svpart ----------------
__global__ __launch_bounds__(256) void k_gpart(const unsigned short* __restrict__ hbf,
                                               const float* __restrict__ H2psi,
                                               float* __restrict__ Gpart,
                                               float* __restrict__ svpart) {
    __shared__ float vt[4096];       // [64 px][64 w]
    __shared__ float h2t[8192];      // [64 px][128 j]
    int blk = blockIdx.x;            // 512
    int b = blk >> 8;
    int n0 = (blk & 255) << 6;
    int t = threadIdx.x;
    int pxq = t >> 2, qq = t & 3;
    int sw = (pxq & 7) << 4;
    {
        const unsigned short* src = hbf + fullpix(b, n0 + pxq) * 64 + qq * 16;
        uint4 u0 = *(const uint4*)src;
        uint4 u1 = *(const uint4*)(src + 8);
        unsigned uv[8] = {u0.x, u0.y, u0.z, u0.w, u1.x, u1.y, u1.z, u1.w};
        float f[16];
#pragma unroll
        for (int i = 0; i < 8; ++i) {
            f[2 * i]     = __uint_as_float((uv[i] & 0xFFFFu) << 16);
            f[2 * i + 1] = __uint_as_float(uv[i] & 0xFFFF0000u);
        }
#pragma unroll
        for (int j = 0; j < 4; ++j) {
            int byte = (pxq * 256 + qq * 64 + j * 16) ^ sw;
            *(float4*)((char*)vt + byte) = make_float4(f[4 * j], f[4 * j + 1],
                                                       f[4 * j + 2], f[4 * j + 3]);
        }
        const float* hsrc = &H2psi[((size_t)(b * 16384 + n0 + pxq)) * 128 + qq * 32];
#pragma unroll
        for (int rr = 0; rr < 8; ++rr) {
            int byte = (pxq * 512 + qq * 128 + rr * 16) ^ sw;
            *(float4*)((char*)h2t + byte) = *(const float4*)(hsrc + rr * 4);
        }
    }
    __syncthreads();

    int wt_ = (t >> 5) << 3;         // 0..56
    int kt  = (t & 31) << 2;         // 0..124
    float acc[8][4];
#pragma unroll
    for (int i = 0; i < 8; ++i)
#pragma unroll
        for (int j = 0; j < 4; ++j) acc[i][j] = 0.f;

#pragma unroll 4
    for (int nn = 0; nn < 64; ++nn) {
        int nsw = (nn & 7) << 4;
        float4 hv = *(float4*)((char*)h2t + ((nn * 512 + kt * 4) ^ nsw));
        float4 v0 = *(float4*)((char*)vt + ((nn * 256 + wt_ * 4) ^ nsw));
        float4 v1 = *(float4*)((char*)vt + ((nn * 256 + wt_ * 4 + 16) ^ nsw));
        float vv[8] = {v0.x, v0.y, v0.z, v0.w, v1.x, v1.y, v1.z, v1.w};
        float hh[4] = {hv.x, hv.y, hv.z, hv.w};
#pragma unroll
        for (int i = 0; i < 8; ++i)
#pragma unroll
            for (int j = 0; j < 4; ++j) acc[i][j] = fmaf(vv[i], hh[j], acc[i][j]);
    }

    float* gp = Gpart + (size_t)blk * 8192;
#pragma unroll
    for (int i = 0; i < 8; ++i)
        *(float4*)&gp[(wt_ + i) * 128 + kt] =
            make_float4(acc[i][0], acc[i][1], acc[i][2], acc[i][3]);

    if (t < 64) {
        float s = 0.f;
#pragma unroll 8
        for (int p = 0; p < 64; ++p)
            s += *(float*)((char*)vt + ((p * 256 + t * 4) ^ ((p & 7) << 4)));
        svpart[blk * 64 + t] = s;
    }
}

// ---------------- reduce: G = sum Gpart; sv = sum svpart (grid 258) ----------------
__global__ __launch_bounds__(256) void k_gred(const float* __restrict__ Gpart,
                                              const float* __restrict__ svpart,
                                              float* __restrict__ G,
                                              float* __restrict__ sv) {
    __shared__ float red[4][64];
    int blk = blockIdx.x;
    int t = threadIdx.x;
    if (blk < 256) {
        int b  = blk >> 7;
        int es = (blk & 127) << 6;
        int e  = es + (t & 63);
        int cg = t >> 6;
        float s = 0.f;
        const float* gp = Gpart + ((size_t)(b * 256 + cg * 64)) * 8192 + e;
#pragma unroll 8
        for (int c = 0; c < 64; ++c) s += gp[(size_t)c * 8192];
        red[cg][t & 63] = s;
        __syncthreads();
        if (t < 64)
            G[b * 8192 + es + t] = red[0][t] + red[1][t] + red[2][t] + red[3][t];
    } else {
        int b = blk - 256;
        int w = t & 63, cg = t >> 6;
        float s = 0.f;
        const float* sp = svpart + ((size_t)(b * 256 + cg * 64)) * 64 + w;
#pragma unroll 8
        for (int c = 0; c < 64; ++c) s += sp[c * 64];
        red[cg][w] = s;
        __syncthreads();
        if (t < 64) sv[b * 64 + t] = red[0][t] + red[1][t] + red[2][t] + red[3][t];
    }
}

// ---------------- yc: ybar -> C[b][w][k], D[b][w] (grid 32) ----------------
__global__ __launch_bounds__(256) void k_yc(const float* __restrict__ G,
                                            const float* __restrict__ sv,
                                            const float* __restrict__ W3psi,
                                            const float* __restrict__ b3psi,
                                            const float* __restrict__ W3phi,
                                            const float* __restrict__ b3phi,
                                            float* __restrict__ C,
                                            float* __restrict__ D) {
    __shared__ float ybar[256];
    int bq = blockIdx.x;             // 32
    int b = bq >> 4, q = bq & 15;
    int t = threadIdx.x;
    {
        int o = t, w = o >> 2;
        const float* gp = &G[(size_t)(b * 64 + w) * 128];
        float s0 = 0.f, s1 = 0.f, s2 = 0.f, s3 = 0.f;
#pragma unroll 4
        for (int k = 0; k < 128; k += 4) {
            s0 = fmaf(W3psi[(k + 0) * 256 + o], gp[k + 0], s0);
            s1 = fmaf(W3psi[(k + 1) * 256 + o], gp[k + 1], s1);
            s2 = fmaf(W3psi[(k + 2) * 256 + o], gp[k + 2], s2);
            s3 = fmaf(W3psi[(k + 3) * 256 + o], gp[k + 3], s3);
        }
        float s = b3psi[o] * sv[b * 64 + w] + ((s0 + s1) + (s2 + s3));
        ybar[o] = s * (1.f / 16384.f);
    }
    __syncthreads();
#pragma unroll
    for (int rep = 0; rep < 2; ++rep) {
        int e = q * 512 + rep * 256 + t;   // this block's slice of 8192
        int w = e >> 7, k = e & 127;
        const float* wp = &W3phi[k * 256 + w * 4];
        C[b * 8192 + e] = fmaf(wp[0], ybar[w * 4],
                          fmaf(wp[1], ybar[w * 4 + 1],
                          fmaf(wp[2], ybar[w * 4 + 2], wp[3] * ybar[w * 4 + 3])));
    }
    if (q == 0 && t < 64) {
        int w = t;
        D[b * 64 + w] = b3phi[w * 4] * ybar[w * 4] + b3phi[w * 4 + 1] * ybar[w * 4 + 1]
                      + b3phi[w * 4 + 2] * ybar[w * 4 + 2] + b3phi[w * 4 + 3] * ybar[w * 4 + 3];
    }
}

// ---------------- x2c: x2c[px][w] = H2phi[px][:].C[b][w][:] + D[b][w] (grid 1024) ----------------
__global__ __launch_bounds__(256) void k_x2c(const float* __restrict__ H2phi,
                                             const float* __restrict__ C,
                                             const float* __restrict__ D,
                                             float* __restrict__ x2c) {
    __shared__ float cl[8192];       // C[b]: [64 w][128 k]  (32 KB)
    __shared__ float h2l[4096];      // [32 px][128 k], XOR-swizzled (16 KB)
    __shared__ float Dl[64];
    int blk = blockIdx.x;            // 1024: 512 per b
    int b = blk >> 9;
    int px0 = (blk & 511) << 5;      // 32 px per block
    int t = threadIdx.x;

    const float* cp = C + b * 8192;
#pragma unroll
    for (int r = 0; r < 8; ++r) {
        int f = r * 1024 + t * 4;
        *(float4*)&cl[f] = *(const float4*)&cp[f];
    }
    if (t < 64) Dl[t] = D[b * 64 + t];
    {   // stage H2phi tile: 4096 floats, coalesced float4 loads, swizzled stores
        const float* hsrc = H2phi + ((size_t)(b * 16384 + px0)) * 128;
#pragma unroll
        for (int r = 0; r < 4; ++r) {
            int f = r * 1024 + t * 4;              // float index
            int px = f >> 7;
            int byte = (f * 4) ^ ((px & 7) << 4) ^ (((px >> 3) & 1) << 6);
            *(float4*)((char*)h2l + byte) = *(const float4*)&hsrc[f];
        }
    }
    __syncthreads();

    int px = t & 31;
    int w0 = (t >> 5) << 3;          // 0..56: 8 w per thread
    int psw = ((px & 7) << 4) ^ (((px >> 3) & 1) << 6);
    float acc[8];
#pragma unroll
    for (int j = 0; j < 8; ++j) acc[j] = 0.f;

#pragma unroll 4
    for (int kq = 0; kq < 32; ++kq) {
        float4 hq = *(float4*)((char*)h2l + ((px * 512 + kq * 16) ^ psw));
#pragma unroll
        for (int j = 0; j < 8; ++j) {
            float4 cq = *(float4*)&cl[(w0 + j) * 128 + kq * 4];
            acc[j] = fmaf(hq.x, cq.x, acc[j]);
            acc[j] = fmaf(hq.y, cq.y, acc[j]);
            acc[j] = fmaf(hq.z, cq.z, acc[j]);
            acc[j] = fmaf(hq.w, cq.w, acc[j]);
        }
    }
    float* op = &x2c[((size_t)(b * 16384 + px0 + px)) * 64 + w0];
    *(float4*)(op)     = make_float4(acc[0] + Dl[w0],     acc[1] + Dl[w0 + 1],
                                     acc[2] + Dl[w0 + 2], acc[3] + Dl[w0 + 3]);
    *(float4*)(op + 4) = make_float4(acc[4] + Dl[w0 + 4], acc[5] + Dl[w0 + 5],
                                     acc[6] + Dl[w0 + 6], acc[7] + Dl[w0 + 7]);
}

// ---------------- epilogue: h = LN(x1 + up(yl1) + up(yl2) + up(x2c)); LDS-staged corners ----------------
__global__ __launch_bounds__(256) void k_epilogue(const float* __restrict__ x1,
                                                  const float* __restrict__ yl1,
                                                  const float* __restrict__ yl2,
                                                  const float* __restrict__ x2c,
                                                  const float* __restrict__ lnG,
                                                  const float* __restrict__ lnB,
                                                  unsigned short* __restrict__ hbf,
                                                  int do_relu) {
    __shared__ float y1s[2][10][64];   // yl1 corners (scale 2)
    __shared__ float xcs[2][10][64];   // x2c corners (scale 2)
    __shared__ float y2s[2][6][64];    // yl2 corners (scale 4)
    int t    = threadIdx.x;
    int blk  = blockIdx.x;                 // 8192 = 2 * 256 * 16
    int b    = blk >> 12;
    int rest = blk & 4095;
    int y    = rest >> 4;
    int x0   = (rest & 15) << 4;
    int wv = t >> 6, lane = t & 63;

    // block-uniform y-lerps and col bases
    Lerp ly1 = lcoord(y, 0.5f, -0.25f, 128);    // yl1 & x2c
    Lerp ly2 = lcoord(y, 0.25f, -0.375f, 64);   // yl2
    int c1 = max(0, (int)floorf((float)x0 * 0.5f - 0.25f));
    int c2 = max(0, (int)floorf((float)x0 * 0.25f - 0.375f));

    // ---- stage corners: 832 float4 slots (Y1 320 | XC 320 | Y2 192) ----
    const float* Y1 = yl1 + (size_t)b * 16384 * 64;
    const float* Y2 = yl2 + (size_t)b * 4096 * 64;
    const float* XC = x2c + (size_t)b * 16384 * 64;
    for (int f4 = t; f4 < 832; f4 += 256) {
        int e, row, col;
        const float* src;
        float* dst;
        if (f4 < 320) {                 // y1s
            e = f4 * 4;
            int r = e / 640, rm = e - r * 640;
            int j = rm >> 6, ch = rm & 63;
            row = r ? ly1.i1 : ly1.i0;
            col = min(c1 + j, 127);
            src = &Y1[((size_t)(row * 128 + col)) * 64 + ch];
            dst = &y1s[r][j][ch];
        } else if (f4 < 640) {          // xcs
            e = (f4 - 320) * 4;
            int r = e / 640, rm = e - r * 640;
            int j = rm >> 6, ch = rm & 63;
            row = r ? ly1.i1 : ly1.i0;
            col = min(c1 + j, 127);
            src = &XC[((size_t)(row * 128 + col)) * 64 + ch];
            dst = &xcs[r][j][ch];
        } else {                        // y2s
            e = (f4 - 640) * 4;
            int r = e / 384, rm = e - r * 384;
            int j = rm >> 6, ch = rm & 63;
            row = r ? ly2.i1 : ly2.i0;
            col = min(c2 + j, 63);
            src = &Y2[((size_t)(row * 64 + col)) * 64 + ch];
            dst = &y2s[r][j][ch];
        }
        *(float4*)dst = *(const float4*)src;
    }
    __syncthreads();

    float g = lnG[lane], be = lnB[lane];
    for (int pp = 0; pp < 4; ++pp) {
        int xx = x0 + wv * 4 + pp;
        size_t pix = (size_t)((b * 256 + y) * 256 + xx);
        float v = x1[pix * 64 + lane];
        {   // yl1 + x2c (shared x-lerp)
            Lerp lx = lcoord(xx, 0.5f, -0.25f, 128);
            int j0 = lx.i0 - c1, j1 = lx.i1 - c1;
            float a0 = y1s[0][j0][lane], a1 = y1s[0][j1][lane];
            float b0 = y1s[1][j0][lane], b1 = y1s[1][j1][lane];
            float ta = a0 + lx.f * (a1 - a0);
            float tb = b0 + lx.f * (b1 - b0);
            v += ta + ly1.f * (tb - ta);
            float p0 = xcs[0][j0][lane], p1 = xcs[0][j1][lane];
            float q0 = xcs[1][j0][lane], q1 = xcs[1][j1][lane];
            float tp = p0 + lx.f * (p1 - p0);
            float tq = q0 + lx.f * (q1 - q0);
            v += tp + ly1.f * (tq - tp);
        }
        {   // yl2
            Lerp lx = lcoord(xx, 0.25f, -0.375f, 64);
            int j0 = lx.i0 - c2, j1 = lx.i1 - c2;
            float a0 = y2s[0][j0][lane], a1 = y2s[0][j1][lane];
            float b0 = y2s[1][j0][lane], b1 = y2s[1][j1][lane];
            float ta = a0 + lx.f * (a1 - a0);
            float tb = b0 + lx.f * (b1 - b0);
            v += ta + ly2.f * (tb - ta);
        }
        float mu  = wave_sum64(v) * (1.f / 64.f);
        float d   = v - mu;
        float var = wave_sum64(d * d) * (1.f / 64.f);
        float ov  = fmaf(d * rsqrtf(var + 1e-5f), g, be);
        if (do_relu) ov = fmaxf(ov, 0.f);
        hbf[pix * 64 + lane] = f2bf(ov);
    }
}

// ---------------- head (MFMA): out = relu(hbf@q1W+q1b) . q2 + q2b ----------------
__global__ __launch_bounds__(256) void k_head_mfma(
    const unsigned short* __restrict__ hbf,   // [131072][64] bf16
    const unsigned short* __restrict__ q1bf,  // [128 j][64 k] bf16
    const float* __restrict__ q1b,            // [128]
    const float* __restrict__ q2,             // [128]
    const float* __restrict__ q2b,            // [1]
    float* __restrict__ out) {
    __shared__ unsigned short Q[8192];        // [j][k] swizzled
    int t = threadIdx.x;
    for (int c = t; c < 1024; c += 256) {
        int j = c >> 3, slot = c & 7;
        uint4 v = *(const uint4*)(q1bf + j * 64 + slot * 8);
        int byte = (j * 128 + slot * 16) ^ ((j & 7) << 4);
        *(uint4*)((char*)Q + byte) = v;
    }
    __syncthreads();

    int w = t >> 6, lane = t & 63;
    int lo = lane & 31, hi = lane >> 5;
    int px0 = blockIdx.x * 128 + w * 32;      // grid 1024

    bf16x8_t av[4];
    const unsigned short* hp = hbf + (size_t)(px0 + lo) * 64 + hi * 8;
#pragma unroll
    for (int ks = 0; ks < 4; ++ks)
        av[ks] = *(const bf16x8_t*)(hp + ks * 16);

    float res[16];
#pragma unroll
    for (int r = 0; r < 16; ++r) res[r] = 0.f;

#pragma unroll
    for (int jb = 0; jb < 4; ++jb) {
        f32x16_t acc = {};
        int j = jb * 32 + lo;
#pragma unroll
        for (int ks = 0; ks < 4; ++ks) {
            int byte = (j * 128 + ks * 32 + hi * 16) ^ ((j & 7) << 4);
            bf16x8_t bv = *(bf16x8_t*)((char*)Q + byte);
            acc = __builtin_amdgcn_mfma_f32_32x32x16_bf16(av[ks], bv, acc, 0, 0, 0);
        }
        float b1 = q1b[j];
        float w2 = q2[j];
#pragma unroll
        for (int r = 0; r < 16; ++r)
            res[r] = fmaf(fmaxf(acc[r] + b1, 0.f), w2, res[r]);
    }
#pragma unroll
    for (int r = 0; r < 16; ++r) {
        float v = res[r];
        v += __shfl_xor(v, 1);
        v += __shfl_xor(v, 2);
        v += __shfl_xor(v, 4);
        v += __shfl_xor(v, 8);
        v += __shfl_xor(v, 16);
        res[r] = v;
    }
    if (lo == 0) {
        float qb = q2b[0];
#pragma unroll
        for (int r = 0; r < 16; ++r) {
            int row = (r & 3) + 8 * (r >> 2) + 4 * hi;
            out[px0 + row] = res[r] + qb;
        }
    }
}

// ---------------- launch ----------------
extern "C" void kernel_launch(void* const* d_in, const int* in_sizes, int n_in,
                              void* d_out, int out_size, void* d_ws, size_t ws_size,
                              hipStream_t stream) {
    const float* x     = (const float*)d_in[0];
    const float* a     = (const float*)d_in[1];
    const float* pW    = (const float*)d_in[2];
    const float* pb    = (const float*)d_in[3];
    const float* q1W   = (const float*)d_in[4];
    const float* q1b   = (const float*)d_in[5];
    const float* q2W   = (const float*)d_in[6];
    const float* q2b   = (const float*)d_in[7];
    const float* phiW1 = (const float*)d_in[8];
    const float* phib1 = (const float*)d_in[9];
    const float* phiW2 = (const float*)d_in[10];
    const float* phib2 = (const float*)d_in[11];
    const float* phiW3 = (const float*)d_in[12];
    const float* phib3 = (const float*)d_in[13];
    const float* psiW1 = (const float*)d_in[14];
    const float* psib1 = (const float*)d_in[15];
    const float* psiW2 = (const float*)d_in[16];
    const float* psib2 = (const float*)d_in[17];
    const float* psiW3 = (const float*)d_in[18];
    const float* psib3 = (const float*)d_in[19];
    const float* lnG   = (const float*)d_in[20];
    const float* lnB   = (const float*)d_in[21];
    const float* convW = (const float*)d_in[22];
    const float* convb = (const float*)d_in[23];

    float* ws    = (float*)d_ws;
    float* x1    = ws + OFF_X1;
    float* yl1   = ws + OFF_YL1;
    float* yl2   = ws + OFF_YL2;
    unsigned short* hbf = (unsigned short*)(ws + OFF_HBF);
    float* H2psi = ws + OFF_H2PSI;
    float* x2c   = ws + OFF_H2PSI;            // overlay: H2psi dead after k_gpart
    float* H2phi = ws + OFF_H2PHI;
    unsigned short* cwtbf = (unsigned short*)(ws + OFF_CWTBF);
    unsigned short* q1bf  = (unsigned short*)(ws + OFF_Q1BF);
    float* Gpart = ws + OFF_GPART;
    float* svpart= ws + OFF_SVP;
    float* G     = ws + OFF_G;
    float* sv    = ws + OFF_SV;
    float* C     = ws + OFF_C;
    float* D     = ws + OFF_D;

    k_transpose_convw_bf<<<1728, 256, 0, stream>>>(convW, cwtbf);
    k_transpose_q1bf<<<32, 256, 0, stream>>>(q1W, q1bf);

    k_lift<<<512, 256, 0, stream>>>(x, a, pW, pb, hbf);

    for (int i = 0; i < 4; ++i) {
        k_conv_mfma<<<1344, 256, 0, stream>>>(hbf, cwtbf, convb, x1, yl1, yl2, i);
        k_mlp12<<<1024, 256, 0, stream>>>(a, x,
                                          psiW1 + i * 192, psib1 + i * 64,
                                          psiW2 + i * 8192, psib2 + i * 128,
                                          phiW1 + i * 192, phib1 + i * 64,
                                          phiW2 + i * 8192, phib2 + i * 128,
                                          H2psi, H2phi);
        k_gpart<<<512, 256, 0, stream>>>(hbf, H2psi, Gpart, svpart);
        k_gred<<<258, 256, 0, stream>>>(Gpart, svpart, G, sv);
        k_yc<<<32, 256, 0, stream>>>(G, sv,
                                     psiW3 + (size_t)i * 32768, psib3 + i * 256,
                                     phiW3 + (size_t)i * 32768, phib3 + i * 256,
                                     C, D);
        k_x2c<<<1024, 256, 0, stream>>>(H2phi, C, D, x2c);
        k_epilogue<<<8192, 256, 0, stream>>>(x1, yl1, yl2, x2c,
                                             lnG + i * 64, lnB + i * 64,
                                             hbf, (i < 3) ? 1 : 0);
    }

    k_head_mfma<<<1024, 256, 0, stream>>>(hbf, q1bf, q1b, q2W, q2b, (float*)d_out);
}